// Round 12
// baseline (161.584 us; speedup 1.0000x reference)
//
#include <hip/hip_runtime.h>
#include <hip/hip_bf16.h>

#define N_SEC 32
#define BDIM 1024
#define DDIM 1024

typedef __attribute__((ext_vector_type(8))) short bf16x8;
typedef __attribute__((ext_vector_type(4))) float f32x4;
typedef __attribute__((ext_vector_type(4))) int i32x4;

#define WAITVM(n) asm volatile("s_waitcnt vmcnt(" #n ")" ::: "memory")

__device__ __forceinline__ void bar() {           // raw barrier + compiler fence
    __builtin_amdgcn_s_barrier();                 // (no vmcnt(0) drain, no sched_barrier)
    asm volatile("" ::: "memory");
}

__device__ __forceinline__ unsigned pk2(float a, float b) {
    union { __hip_bfloat162 h; unsigned u; } cv;
    cv.h = __float22bfloat162_rn(make_float2(a, b));
    return cv.u;
}

__device__ __forceinline__ i32x4 pack8(float4 a, float4 b) {
    i32x4 r;
    r[0] = pk2(a.x, a.y); r[1] = pk2(a.z, a.w);
    r[2] = pk2(b.x, b.y); r[3] = pk2(b.z, b.w);
    return r;
}

__device__ __forceinline__ f32x4 mfma16(bf16x8 a, bf16x8 b, f32x4 c) {
    return __builtin_amdgcn_mfma_f32_16x16x32_bf16(a, b, c, 0, 0, 0);
}

__device__ __forceinline__ float wave_sum(float v) {
    #pragma unroll
    for (int off = 32; off > 0; off >>= 1) v += __shfl_down(v, off, 64);
    return v;
}

__device__ __forceinline__ void gload16(const unsigned short* g, unsigned short* l) {
    __builtin_amdgcn_global_load_lds(
        (const __attribute__((address_space(1))) unsigned int*)g,
        (__attribute__((address_space(3))) unsigned int*)l, 16, 0, 0);
}

// ---------------------------------------------------------------------------
// Path A: prep, zero, gramE (enc split-K symmetric atomic gram), cvt0,
// fused (secret blocks 0..255 | gram blocks 256..1407), fin2.
// gram = 128^2/4-wave/BK32, 2-buffer, double-light-barrier, WAITVM(4):
//   {bar1; stage(kt+1 -> buf^1); vmcnt(4); bar2; compute(kt)}
// Overwrite-safe: victim last read before bar1. Publish-safe: every wave
// retires its own tile-kt loads (vmcnt(4)) before bar2.
// ---------------------------------------------------------------------------

__global__ void prep_k(const float* __restrict__ outp, const float* __restrict__ enc,
                       unsigned short* __restrict__ Xb, unsigned short* __restrict__ Eb,
                       float* __restrict__ sq_out, float* __restrict__ sq_enc) {
    int wid = threadIdx.x >> 6, l = threadIdx.x & 63;
    int r = blockIdx.x * 4 + wid;
    bool isOut = r < N_SEC * BDIM;
    const float* src = isOut ? (outp + (size_t)r * DDIM)
                             : (enc + (size_t)(r - N_SEC * BDIM) * DDIM);
    unsigned short* dst = isOut ? (Xb + (size_t)r * DDIM)
                                : (Eb + (size_t)(r - N_SEC * BDIM) * DDIM);
    const float4* s4 = (const float4*)src;
    float s = 0.f;
    #pragma unroll
    for (int h = 0; h < 2; ++h) {
        int c = l + h * 64;
        float4 v0 = s4[2 * c], v1 = s4[2 * c + 1];
        i32x4 p = pack8(v0, v1);
        *(i32x4*)&dst[c * 8] = p;
        #pragma unroll
        for (int e = 0; e < 4; ++e) {
            unsigned u = (unsigned)p[e];
            float a = __uint_as_float(u << 16);
            float b = __uint_as_float(u & 0xFFFF0000u);
            s += a * a + b * b;
        }
    }
    s = wave_sum(s);
    if (l == 0) { if (isOut) sq_out[r] = s; else sq_enc[r - N_SEC * BDIM] = s; }
}

__global__ void zero_k(float* __restrict__ p) {
    int i = blockIdx.x * blockDim.x + threadIdx.x;       // 512*256*2 = 256K f4
    float4 z = {0.f, 0.f, 0.f, 0.f};
    ((float4*)p)[i] = z;
    ((float4*)p)[i + 131072] = z;
}

// In-place: g -> sqrt(max(sq[i]+sq[j]-2g,0)+eps) over the full 1024x1024 plane.
__global__ void cvt0_k(float* __restrict__ d, const float* __restrict__ sq) {
    int t = blockIdx.x * blockDim.x + threadIdx.x;
    #pragma unroll
    for (int h = 0; h < 2; ++h) {
        int idx = t + h * 131072;
        int i = idx >> 8;
        float si = sq[i];
        float4 g = ((const float4*)d)[idx];
        int j0 = (idx & 255) * 4;
        float4 r;
        r.x = sqrtf(fmaxf(si + sq[j0 + 0] - 2.f * g.x, 0.f) + 1e-12f);
        r.y = sqrtf(fmaxf(si + sq[j0 + 1] - 2.f * g.y, 0.f) + 1e-12f);
        r.z = sqrtf(fmaxf(si + sq[j0 + 2] - 2.f * g.z, 0.f) + 1e-12f);
        r.w = sqrtf(fmaxf(si + sq[j0 + 3] - 2.f * g.w, 0.f) + 1e-12f);
        ((float4*)d)[idx] = r;
    }
}

// enc gram, split-K: 36 upper tiles x 4 K-slices, symmetric atomic gram out.
template<int NIT>
__global__ void gramE_k(const unsigned short* __restrict__ Xb, float* __restrict__ gw) {
    int tile = blockIdx.x >> 2;
    int kbeg = (blockIdx.x & 3) * NIT;
    int idx = tile, ti = 0;
    while (idx >= 8 - ti) { idx -= 8 - ti; ti++; }
    int tj = ti + idx;
    const unsigned short* Xn = Xb;
    int i0 = ti * 128, j0 = tj * 128;
    bool diag = (ti == tj);

    __shared__ __align__(16) unsigned short Ash[3][4096];
    __shared__ __align__(16) unsigned short Bsh[3][4096];

    int t = threadIdx.x, wid = t >> 6, l = t & 63;
    int wr = wid >> 1, wc = wid & 1;
    bool dead = diag && (wr > wc);
    int cg = l >> 4, lr = l & 15;

    f32x4 acc[4][4];
    #pragma unroll
    for (int a = 0; a < 4; a++)
        #pragma unroll
        for (int c = 0; c < 4; c++) acc[a][c] = f32x4{0.f, 0.f, 0.f, 0.f};

    int eoffA[4], eoffB[4];
    #pragma unroll
    for (int f = 0; f < 4; f++) {
        int ra = wr * 64 + f * 16 + lr;
        eoffA[f] = ra * 32 + ((cg ^ ((ra >> 1) & 3)) * 8);
        int rb = wc * 64 + f * 16 + lr;
        eoffB[f] = rb * 32 + ((cg ^ ((rb >> 1) & 3)) * 8);
    }
    int rs = wid * 16 + (l >> 2);
    int cgs = (l & 3) ^ ((rs >> 1) & 3);
    const unsigned short* gA0 = Xn + (size_t)(i0 + rs) * DDIM + cgs * 8;
    const unsigned short* gA1 = gA0 + (size_t)64 * DDIM;
    const unsigned short* gB0 = Xn + (size_t)(j0 + rs) * DDIM + cgs * 8;
    const unsigned short* gB1 = gB0 + (size_t)64 * DDIM;

    auto stage = [&](int buf, int kt) {
        int ko = kt * 32;
        gload16(gA0 + ko, &Ash[buf][wid * 512]);
        gload16(gA1 + ko, &Ash[buf][2048 + wid * 512]);
        gload16(gB0 + ko, &Bsh[buf][wid * 512]);
        gload16(gB1 + ko, &Bsh[buf][2048 + wid * 512]);
    };
    auto compute = [&](int buf) {
        if (dead) return;
        bf16x8 af[4], bfr[4];
        #pragma unroll
        for (int f = 0; f < 4; f++) {
            af[f]  = *(const bf16x8*)&Ash[buf][eoffA[f]];
            bfr[f] = *(const bf16x8*)&Bsh[buf][eoffB[f]];
        }
        #pragma unroll
        for (int fi = 0; fi < 4; fi++)
            #pragma unroll
            for (int fj = 0; fj < 4; fj++) {
                if (diag && wr == wc && fj < fi) continue;
                acc[fi][fj] = mfma16(af[fi], bfr[fj], acc[fi][fj]);
            }
    };

    int klast = kbeg + NIT - 1;
#define GSTEP(SB, CB) do {                       \
        int nx = c + 1; if (nx > klast) nx = klast; \
        stage(SB, nx);                           \
        WAITVM(4);                               \
        bar();                                   \
        compute(CB);                             \
        ++c; } while (0)
    stage(0, kbeg);
    int c = kbeg;
    #pragma unroll 1
    for (int it = 0; it < NIT / 3; ++it) { GSTEP(1, 0); GSTEP(2, 1); GSTEP(0, 2); }
    if (NIT % 3 >= 1) GSTEP(1, 0);
    if (NIT % 3 >= 2) GSTEP(2, 1);
#undef GSTEP
    asm volatile("s_waitcnt vmcnt(0)" ::: "memory");

    if (!dead) {
        #pragma unroll
        for (int fi = 0; fi < 4; fi++)
            #pragma unroll
            for (int fj = 0; fj < 4; fj++) {
                if (diag && wr == wc && fj < fi) continue;
                int jg = j0 + wc * 64 + fj * 16 + lr;
                #pragma unroll
                for (int e = 0; e < 4; e++) {
                    int ig = i0 + wr * 64 + fi * 16 + cg * 4 + e;
                    float g = acc[fi][fj][e];
                    if (jg >= ig) atomicAdd(&gw[(size_t)ig * BDIM + jg], g);
                    if (jg > ig)  atomicAdd(&gw[(size_t)jg * BDIM + ig], g);
                }
            }
    }
}

// Fused: blocks 0..255 secret (32KB-LDS variant), 256..1407 gram (1152).
__global__ void fused_k(const unsigned short* __restrict__ Xb,
                        const float* __restrict__ sq_out,
                        const float* __restrict__ dsent,
                        float* __restrict__ ps, float* __restrict__ psec) {
    __shared__ __align__(16) unsigned short SH[16384];   // 32 KB, shared by paths
    __shared__ float red[4];
    int t = threadIdx.x, wid = t >> 6, l = t & 63;
    int cg = l >> 4, lr = l & 15;

    if (blockIdx.x < 256) {
        // ---- secret path: 4 b per block; 16 kt steps of 64 cols; [n][b][ch] ----
        int b0 = blockIdx.x * 4;
        f32x4 a00 = {0.f,0.f,0.f,0.f}, a01 = {0.f,0.f,0.f,0.f}, a11 = {0.f,0.f,0.f,0.f};
        int nbase = wid * 2;
        auto sstage = [&](int buf, int kt) {      // 4 loads/thread
            #pragma unroll
            for (int m = 0; m < 4; ++m) {
                int nn = m * 8 + nbase + (l >> 5);
                int bb = b0 + ((l >> 3) & 3);
                int ch = (l & 7) ^ (nn & 7);      // pre-swizzled source chunk
                gload16(Xb + ((size_t)(nn * BDIM + bb)) * DDIM + kt * 64 + ch * 8,
                        &SH[buf * 8192 + (m * 8 + nbase) * 256]);
            }
        };
        auto scompute = [&](int buf) {
            #pragma unroll
            for (int k2 = 0; k2 < 2; ++k2) {
                int cs = k2 * 4 + cg;             // 0..7
                int cl = (cs ^ (lr & 7)) * 8;     // (16+lr)&7 == lr&7
                bf16x8 u0 = *(const bf16x8*)&SH[buf * 8192 + lr * 256 + wid * 64 + cl];
                bf16x8 u1 = *(const bf16x8*)&SH[buf * 8192 + (16 + lr) * 256 + wid * 64 + cl];
                a00 = mfma16(u0, u0, a00);
                a01 = mfma16(u0, u1, a01);
                a11 = mfma16(u1, u1, a11);
            }
        };
        sstage(0, 0);
        __syncthreads();
        for (int kt = 0; kt < 14; kt += 2) {
            sstage(1, kt + 1); scompute(0); __syncthreads();
            sstage(0, kt + 2); scompute(1); __syncthreads();
        }
        sstage(1, 15); scompute(0); __syncthreads(); scompute(1);

        float lsum = 0.f;
        int b = b0 + wid;
        auto proc = [&](const f32x4& acc, int rb, int cb) {
            #pragma unroll
            for (int e = 0; e < 4; e++) {
                int i = rb * 16 + cg * 4 + e;
                int j = cb * 16 + lr;
                if (j > i) {
                    float d2 = sq_out[(size_t)i * BDIM + b] + sq_out[(size_t)j * BDIM + b] - 2.f * acc[e];
                    float d = sqrtf(fmaxf(d2, 0.f) + 1e-12f);
                    lsum += fmaxf(1.f - d, 0.f);
                }
            }
        };
        proc(a00, 0, 0); proc(a01, 0, 1); proc(a11, 1, 1);
        lsum = wave_sum(lsum);
        if (l == 0) red[wid] = lsum;
        __syncthreads();
        if (t == 0) psec[blockIdx.x] = red[0] + red[1] + red[2] + red[3];
        return;
    }

    // ---- gram path: 128^2 triangle tile, 2-buffer double-light-barrier ----
    int g = blockIdx.x - 256;                 // 0..1151
    int xcd = g & 7, local = g >> 3;
    int n = xcd * 4 + local / 36;             // 4 consecutive n per XCD
    int tile = local % 36;
    int idx = tile, ti = 0;
    while (idx >= 8 - ti) { idx -= 8 - ti; ti++; }
    int tj = ti + idx;
    const unsigned short* Xn = Xb + (size_t)n * BDIM * DDIM;
    const float* sqn = sq_out + n * BDIM;
    int i0 = ti * 128, j0 = tj * 128;
    bool diag = (ti == tj);

    int wr = wid >> 1, wc = wid & 1;
    bool dead = diag && (wr > wc);

    f32x4 acc[4][4];
    #pragma unroll
    for (int a = 0; a < 4; a++)
        #pragma unroll
        for (int c = 0; c < 4; c++) acc[a][c] = f32x4{0.f, 0.f, 0.f, 0.f};

    int eoffA[4], eoffB[4];
    #pragma unroll
    for (int f = 0; f < 4; f++) {
        int ra = wr * 64 + f * 16 + lr;
        eoffA[f] = ra * 32 + ((cg ^ ((ra >> 1) & 3)) * 8);
        int rb = wc * 64 + f * 16 + lr;
        eoffB[f] = rb * 32 + ((cg ^ ((rb >> 1) & 3)) * 8);
    }

    int rs = wid * 16 + (l >> 2);
    int cgs = (l & 3) ^ ((rs >> 1) & 3);
    const unsigned short* gA0 = Xn + (size_t)(i0 + rs) * DDIM + cgs * 8;
    const unsigned short* gA1 = gA0 + (size_t)64 * DDIM;
    const unsigned short* gB0 = Xn + (size_t)(j0 + rs) * DDIM + cgs * 8;
    const unsigned short* gB1 = gB0 + (size_t)64 * DDIM;

    auto stage = [&](int buf, int kt) {       // 4 VMEM ops per thread
        int ko = kt * 32;
        gload16(gA0 + ko, &SH[buf * 4096 + wid * 512]);
        gload16(gA1 + ko, &SH[buf * 4096 + 2048 + wid * 512]);
        gload16(gB0 + ko, &SH[8192 + buf * 4096 + wid * 512]);
        gload16(gB1 + ko, &SH[8192 + buf * 4096 + 2048 + wid * 512]);
    };
    auto compute = [&](int buf) {
        if (dead) return;
        bf16x8 af[4], bfr[4];
        #pragma unroll
        for (int f = 0; f < 4; f++) {
            af[f]  = *(const bf16x8*)&SH[buf * 4096 + eoffA[f]];
            bfr[f] = *(const bf16x8*)&SH[8192 + buf * 4096 + eoffB[f]];
        }
        #pragma unroll
        for (int fi = 0; fi < 4; fi++)
            #pragma unroll
            for (int fj = 0; fj < 4; fj++) {
                if (diag && wr == wc && fj < fi) continue;
                acc[fi][fj] = mfma16(af[fi], bfr[fj], acc[fi][fj]);
            }
    };

#define GSTEP(NB, CB) do {                       \
        bar();                                   \
        int nx = c + 1; if (nx > 31) nx = 31;    \
        stage(NB, nx);                           \
        WAITVM(4);                               \
        bar();                                   \
        compute(CB);                             \
        ++c; } while (0)

    stage(0, 0);
    int c = 0;
    #pragma unroll 1
    for (int it = 0; it < 16; ++it) {            // 32 computes, tiles 0..31
        GSTEP(1, 0);
        GSTEP(0, 1);
    }
#undef GSTEP
    asm volatile("s_waitcnt vmcnt(0)" ::: "memory");   // drain before exit

    float lsum = 0.f;
    if (!dead) {
        #pragma unroll
        for (int fi = 0; fi < 4; fi++) {
            #pragma unroll
            for (int fj = 0; fj < 4; fj++) {
                if (diag && wr == wc && fj < fi) continue;
                int jg = j0 + wc * 64 + fj * 16 + lr;
                #pragma unroll
                for (int e = 0; e < 4; e++) {
                    int ig = i0 + wr * 64 + fi * 16 + cg * 4 + e;
                    float gg = acc[fi][fj][e];
                    float d2 = sqn[ig] + sqn[jg] - 2.f * gg;
                    float d = sqrtf(fmaxf(d2, 0.f) + 1e-12f);
                    if (!diag || jg > ig) {
                        float diff = d - dsent[(size_t)ig * BDIM + jg];
                        lsum += diff * diff;
                    }
                }
            }
        }
    }
    lsum = wave_sum(lsum * 2.f);                 // strict upper counted twice
    if (l == 0) red[wid] = lsum;
    __syncthreads();
    if (t == 0) ps[g] = red[0] + red[1] + red[2] + red[3];
}

// Reduce partials (1152 sentence + 256 secret) and write the 3 outputs.
__global__ void fin2_k(const float* __restrict__ ps, const float* __restrict__ psec,
                       float* __restrict__ out) {
    __shared__ float red[16];
    int t = threadIdx.x;
    float s = 0.f;
    for (int i = t; i < 36 * N_SEC; i += 256) s += ps[i];
    float s2 = psec[t];
    s = wave_sum(s);
    s2 = wave_sum(s2);
    if ((t & 63) == 0) { red[t >> 6] = s; red[8 + (t >> 6)] = s2; }
    __syncthreads();
    if (t == 0) {
        float a = red[0] + red[1] + red[2] + red[3];
        float b = red[8] + red[9] + red[10] + red[11];
        float sl = a * (1.0f / 33554432.0f);           // / (N*B*B)
        float sec = b * (1.0f / (1024.0f * 496.0f));   // / B / n_pairs
        out[0] = 0.5f * sl + 0.5f * sec;
        out[1] = sl;
        out[2] = sec;
    }
}

// ---------------------------------------------------------------------------
// Path B (fallback, known-good): fp32 reads + in-loop convert.
// ---------------------------------------------------------------------------

__global__ void norms_k(const float* __restrict__ outp, const float* __restrict__ enc,
                        float* __restrict__ sq_out, float* __restrict__ sq_enc) {
    int wid = threadIdx.x >> 6, l = threadIdx.x & 63;
    int r = blockIdx.x * 4 + wid;
    const float* src = (r < N_SEC * BDIM) ? (outp + (size_t)r * DDIM)
                                          : (enc + (size_t)(r - N_SEC * BDIM) * DDIM);
    float s = 0.f;
    #pragma unroll
    for (int q = 0; q < 4; q++) {
        float4 v = reinterpret_cast<const float4*>(src)[l + q * 64];
        unsigned u0 = pk2(v.x, v.y), u1 = pk2(v.z, v.w);
        float a = __uint_as_float(u0 << 16), b = __uint_as_float(u0 & 0xFFFF0000u);
        float c = __uint_as_float(u1 << 16), d = __uint_as_float(u1 & 0xFFFF0000u);
        s += a * a + b * b + c * c + d * d;
    }
    s = wave_sum(s);
    if (l == 0) { if (r < N_SEC * BDIM) sq_out[r] = s; else sq_enc[r - N_SEC * BDIM] = s; }
}

template<int MODE>
__global__ void gram_k(const float* __restrict__ X, const float* __restrict__ sqv,
                       const float* __restrict__ dsent_r, float* __restrict__ dsent_w,
                       float* __restrict__ accum) {
    int idx = blockIdx.x, ti = 0;
    while (idx >= 8 - ti) { idx -= 8 - ti; ti++; }
    int tj = ti + idx;
    int n = (MODE == 1) ? blockIdx.y : 0;
    const float* Xn = X + (size_t)n * BDIM * DDIM;
    const float* sqn = sqv + n * BDIM;
    int i0 = ti * 128, j0 = tj * 128;
    bool diag = (ti == tj);
    __shared__ __align__(16) unsigned short Ash[128 * 32];
    __shared__ __align__(16) unsigned short Bsh[128 * 32];
    int t = threadIdx.x, wid = t >> 6, l = t & 63;
    int wr = wid >> 1, wc = wid & 1;
    bool dead = diag && (wr > wc);
    int cg = l >> 4, lr = l & 15;
    f32x4 acc[4][4];
    #pragma unroll
    for (int a = 0; a < 4; a++)
        #pragma unroll
        for (int c = 0; c < 4; c++) acc[a][c] = f32x4{0.f, 0.f, 0.f, 0.f};
    int r0 = t >> 2, c0 = t & 3;
    int swz0 = (c0 ^ (r0 & 3)) * 8;
    int off0 = r0 * 32 + swz0;
    int off1 = (r0 + 64) * 32 + swz0;
    for (int kt = 0; kt < DDIM / 32; ++kt) {
        int k0 = kt * 32;
        const float4* pa0 = (const float4*)(Xn + (size_t)(i0 + r0) * DDIM + k0 + c0 * 8);
        const float4* pa1 = (const float4*)(Xn + (size_t)(i0 + r0 + 64) * DDIM + k0 + c0 * 8);
        const float4* pb0 = (const float4*)(Xn + (size_t)(j0 + r0) * DDIM + k0 + c0 * 8);
        const float4* pb1 = (const float4*)(Xn + (size_t)(j0 + r0 + 64) * DDIM + k0 + c0 * 8);
        float4 a00 = pa0[0], a01 = pa0[1];
        float4 a10 = pa1[0], a11 = pa1[1];
        float4 b00 = pb0[0], b01 = pb0[1];
        float4 b10 = pb1[0], b11 = pb1[1];
        __syncthreads();
        *(i32x4*)&Ash[off0] = pack8(a00, a01);
        *(i32x4*)&Ash[off1] = pack8(a10, a11);
        *(i32x4*)&Bsh[off0] = pack8(b00, b01);
        *(i32x4*)&Bsh[off1] = pack8(b10, b11);
        __syncthreads();
        if (!dead) {
            bf16x8 af[4], bfr[4];
            #pragma unroll
            for (int f = 0; f < 4; f++) {
                int ra = wr * 64 + f * 16 + lr;
                af[f] = *(const bf16x8*)&Ash[ra * 32 + ((cg ^ (ra & 3)) * 8)];
                int rb = wc * 64 + f * 16 + lr;
                bfr[f] = *(const bf16x8*)&Bsh[rb * 32 + ((cg ^ (rb & 3)) * 8)];
            }
            #pragma unroll
            for (int fi = 0; fi < 4; fi++)
                #pragma unroll
                for (int fj = 0; fj < 4; fj++) {
                    if (diag && wr == wc && fj < fi) continue;
                    acc[fi][fj] = mfma16(af[fi], bfr[fj], acc[fi][fj]);
                }
        }
    }
    if (!dead) {
        float lsum = 0.f;
        #pragma unroll
        for (int fi = 0; fi < 4; fi++) {
            #pragma unroll
            for (int fj = 0; fj < 4; fj++) {
                if (diag && wr == wc && fj < fi) continue;
                int jg = j0 + wc * 64 + fj * 16 + lr;
                #pragma unroll
                for (int e = 0; e < 4; e++) {
                    int ig = i0 + wr * 64 + fi * 16 + cg * 4 + e;
                    float g = acc[fi][fj][e];
                    float d2 = sqn[ig] + sqn[jg] - 2.f * g;
                    float d = sqrtf(fmaxf(d2, 0.f) + 1e-12f);
                    if (MODE == 0) {
                        dsent_w[(size_t)ig * BDIM + jg] = d;
                    } else {
                        if (!diag || jg > ig) {
                            float diff = d - dsent_r[(size_t)ig * BDIM + jg];
                            lsum += diff * diff;
                        }
                    }
                }
            }
        }
        if (MODE == 1) {
            lsum = wave_sum(lsum * 2.f);
            if (l == 0) atomicAdd(accum, lsum);
        }
    }
}

__global__ void secret_k(const float* __restrict__ X, const float* __restrict__ sq_out,
                         float* __restrict__ accum) {
    int wid = threadIdx.x >> 6, l = threadIdx.x & 63;
    int b = blockIdx.x * 4 + wid;
    int cg = l >> 4, lr = l & 15;
    f32x4 a00 = {0.f,0.f,0.f,0.f}, a01 = {0.f,0.f,0.f,0.f}, a11 = {0.f,0.f,0.f,0.f};
    for (int kt = 0; kt < 32; ++kt) {
        int k0 = kt * 32 + cg * 8;
        const float4* p0 = (const float4*)(X + ((size_t)lr * BDIM + b) * DDIM + k0);
        const float4* p1 = (const float4*)(X + ((size_t)(16 + lr) * BDIM + b) * DDIM + k0);
        union { i32x4 i; bf16x8 s; } u0, u1;
        u0.i = pack8(p0[0], p0[1]);
        u1.i = pack8(p1[0], p1[1]);
        a00 = mfma16(u0.s, u0.s, a00);
        a01 = mfma16(u0.s, u1.s, a01);
        a11 = mfma16(u1.s, u1.s, a11);
    }
    float lsum = 0.f;
    auto proc = [&](const f32x4& acc, int rb, int cb) {
        #pragma unroll
        for (int e = 0; e < 4; e++) {
            int i = rb * 16 + cg * 4 + e;
            int j = cb * 16 + lr;
            if (j > i) {
                float d2 = sq_out[(size_t)i * BDIM + b] + sq_out[(size_t)j * BDIM + b] - 2.f * acc[e];
                float d = sqrtf(fmaxf(d2, 0.f) + 1e-12f);
                lsum += fmaxf(1.f - d, 0.f);
            }
        }
    };
    proc(a00, 0, 0); proc(a01, 0, 1); proc(a11, 1, 1);
    lsum = wave_sum(lsum);
    if (l == 0) atomicAdd(accum, lsum);
}

__global__ void init_k(float* sums) { sums[threadIdx.x] = 0.f; }

__global__ void fin_k(const float* __restrict__ sums, float* __restrict__ out) {
    float sl = sums[0] * (1.0f / 33554432.0f);
    float sec = sums[1] * (1.0f / (1024.0f * 496.0f));
    out[0] = 0.5f * sl + 0.5f * sec;
    out[1] = sl;
    out[2] = sec;
}

extern "C" void kernel_launch(void* const* d_in, const int* in_sizes, int n_in,
                              void* d_out, int out_size, void* d_ws, size_t ws_size,
                              hipStream_t stream) {
    const float* outputs = (const float*)d_in[0];   // [32,1024,1024] f32
    const float* enc     = (const float*)d_in[1];   // [1024,1024] f32
    float* out = (float*)d_out;                     // 3 floats

    float* ps     = (float*)d_ws;
    float* psec   = ps + 1536;
    float* sq_out = ps + 2048;
    float* sq_enc = sq_out + N_SEC * BDIM;
    float* dsent  = sq_enc + BDIM;
    unsigned short* Xbf = (unsigned short*)(dsent + (size_t)BDIM * BDIM);
    unsigned short* Ebf = Xbf + (size_t)N_SEC * BDIM * DDIM;

    const size_t NEED = 4 * (2048 + (size_t)N_SEC * BDIM + BDIM + (size_t)BDIM * BDIM)
                      + 2 * ((size_t)N_SEC * BDIM * DDIM + (size_t)BDIM * DDIM);

    if (ws_size >= NEED) {
        hipLaunchKernelGGL(prep_k, dim3((N_SEC * BDIM + BDIM) / 4), dim3(256), 0, stream,
                           outputs, enc, Xbf, Ebf, sq_out, sq_enc);
        hipLaunchKernelGGL(zero_k, dim3(512), dim3(256), 0, stream, dsent);
        hipLaunchKernelGGL((gramE_k<8>), dim3(36 * 4), dim3(256), 0, stream, Ebf, dsent);
        hipLaunchKernelGGL(cvt0_k, dim3(512), dim3(256), 0, stream, dsent, sq_enc);
        hipLaunchKernelGGL(fused_k, dim3(256 + 1152), dim3(256), 0, stream,
                           Xbf, sq_out, dsent, ps, psec);
        hipLaunchKernelGGL(fin2_k, dim3(1), dim3(256), 0, stream, ps, psec, out);
    } else {
        float* sums = (float*)d_ws;
        float* fsq_out = sums + 64;
        float* fsq_enc = fsq_out + N_SEC * BDIM;
        float* fdsent  = fsq_enc + BDIM;
        hipLaunchKernelGGL(init_k, dim3(1), dim3(2), 0, stream, sums);
        hipLaunchKernelGGL(norms_k, dim3((N_SEC * BDIM + BDIM) / 4), dim3(256), 0, stream,
                           outputs, enc, fsq_out, fsq_enc);
        hipLaunchKernelGGL((gram_k<0>), dim3(36), dim3(256), 0, stream,
                           enc, fsq_enc, (const float*)nullptr, fdsent, (float*)nullptr);
        hipLaunchKernelGGL((gram_k<1>), dim3(36, N_SEC), dim3(256), 0, stream,
                           outputs, fsq_out, (const float*)fdsent, (float*)nullptr, &sums[0]);
        hipLaunchKernelGGL(secret_k, dim3(BDIM / 4), dim3(256), 0, stream,
                           outputs, fsq_out, &sums[1]);
        hipLaunchKernelGGL(fin_k, dim3(1), dim3(1), 0, stream, sums, out);
    }
}

// Round 13
// 147.131 us; speedup vs baseline: 1.0982x; 1.0982x over previous
//
#include <hip/hip_runtime.h>
#include <hip/hip_bf16.h>

#define N_SEC 32
#define BDIM 1024
#define DDIM 1024

typedef __attribute__((ext_vector_type(8))) short bf16x8;
typedef __attribute__((ext_vector_type(4))) float f32x4;
typedef __attribute__((ext_vector_type(4))) int i32x4;

#define WAITVM(n) asm volatile("s_waitcnt vmcnt(" #n ")" ::: "memory")

__device__ __forceinline__ void bar() {           // raw barrier + compiler fence
    __builtin_amdgcn_s_barrier();                 // (NO sched_barrier - m141)
    asm volatile("" ::: "memory");
}

__device__ __forceinline__ unsigned pk2(float a, float b) {
    union { __hip_bfloat162 h; unsigned u; } cv;
    cv.h = __float22bfloat162_rn(make_float2(a, b));
    return cv.u;
}

__device__ __forceinline__ i32x4 pack8(float4 a, float4 b) {
    i32x4 r;
    r[0] = pk2(a.x, a.y); r[1] = pk2(a.z, a.w);
    r[2] = pk2(b.x, b.y); r[3] = pk2(b.z, b.w);
    return r;
}

__device__ __forceinline__ f32x4 mfma16(bf16x8 a, bf16x8 b, f32x4 c) {
    return __builtin_amdgcn_mfma_f32_16x16x32_bf16(a, b, c, 0, 0, 0);
}

__device__ __forceinline__ float wave_sum(float v) {
    #pragma unroll
    for (int off = 32; off > 0; off >>= 1) v += __shfl_down(v, off, 64);
    return v;
}

__device__ __forceinline__ void gload16(const unsigned short* g, unsigned short* l) {
    __builtin_amdgcn_global_load_lds(
        (const __attribute__((address_space(1))) unsigned int*)g,
        (__attribute__((address_space(3))) unsigned int*)l, 16, 0, 0);
}

// ---------------------------------------------------------------------------
// Path A: prep, zero, gram8<2> (enc split-K, atomic gram), cvt0,
// gram8<1> (3-buf publish-safe counted-vmcnt), secret4, fin2.
// ---------------------------------------------------------------------------

__global__ void prep_k(const float* __restrict__ outp, const float* __restrict__ enc,
                       unsigned short* __restrict__ Xb, unsigned short* __restrict__ Eb,
                       float* __restrict__ sq_out, float* __restrict__ sq_enc) {
    int wid = threadIdx.x >> 6, l = threadIdx.x & 63;
    int r = blockIdx.x * 4 + wid;
    bool isOut = r < N_SEC * BDIM;
    const float* src = isOut ? (outp + (size_t)r * DDIM)
                             : (enc + (size_t)(r - N_SEC * BDIM) * DDIM);
    unsigned short* dst = isOut ? (Xb + (size_t)r * DDIM)
                                : (Eb + (size_t)(r - N_SEC * BDIM) * DDIM);
    const float4* s4 = (const float4*)src;
    float s = 0.f;
    #pragma unroll
    for (int h = 0; h < 2; ++h) {
        int c = l + h * 64;
        float4 v0 = s4[2 * c], v1 = s4[2 * c + 1];
        i32x4 p = pack8(v0, v1);
        *(i32x4*)&dst[c * 8] = p;
        #pragma unroll
        for (int e = 0; e < 4; ++e) {
            unsigned u = (unsigned)p[e];
            float a = __uint_as_float(u << 16);
            float b = __uint_as_float(u & 0xFFFF0000u);
            s += a * a + b * b;
        }
    }
    s = wave_sum(s);
    if (l == 0) { if (isOut) sq_out[r] = s; else sq_enc[r - N_SEC * BDIM] = s; }
}

__global__ void zero_k(float* __restrict__ p) {
    int i = blockIdx.x * blockDim.x + threadIdx.x;       // 512*256*2 = 256K f4
    float4 z = {0.f, 0.f, 0.f, 0.f};
    ((float4*)p)[i] = z;
    ((float4*)p)[i + 131072] = z;
}

// In-place: g -> sqrt(max(sq[i]+sq[j]-2g,0)+eps) over the 1024x1024 plane.
__global__ void cvt0_k(float* __restrict__ d, const float* __restrict__ sq) {
    int t = blockIdx.x * blockDim.x + threadIdx.x;       // 512 blocks * 256
    #pragma unroll
    for (int h = 0; h < 2; ++h) {
        int idx = t + h * 131072;                        // float4 index
        int i = idx >> 8;                                // (idx*4)>>10
        float si = sq[i];
        float4 g = ((const float4*)d)[idx];
        int j0 = (idx & 255) * 4;
        float4 r;
        r.x = sqrtf(fmaxf(si + sq[j0 + 0] - 2.f * g.x, 0.f) + 1e-12f);
        r.y = sqrtf(fmaxf(si + sq[j0 + 1] - 2.f * g.y, 0.f) + 1e-12f);
        r.z = sqrtf(fmaxf(si + sq[j0 + 2] - 2.f * g.z, 0.f) + 1e-12f);
        r.w = sqrtf(fmaxf(si + sq[j0 + 3] - 2.f * g.w, 0.f) + 1e-12f);
        ((float4*)d)[idx] = r;
    }
}

// 128x128 tile, 4 waves 2x2, BK=32. 3-buffer publish-safe pipeline:
// iter kt: stage tile kt+1 into buf (kt+1)%3 (victim last read iter kt-2:
// safe, waves within one barrier of each other) -> WAITVM(4) (retire OWN
// tile-kt loads; tile kt+1 in flight) -> barrier (ALL waves retired tile-kt
// -> publish) -> compute(kt%3). One barrier/iter; vmcnt never drained.
// MODE 1: full K, per-block partial of 2*(d_out-d_sent)^2.
// MODE 2: K-slice [kbeg,kbeg+NIT), atomicAdd raw gram into dsent_w (enc).
template<int MODE, int NIT>
__global__ void gram8_k(const unsigned short* __restrict__ Xb, const float* __restrict__ sqv,
                        const float* __restrict__ dsent_r, float* __restrict__ dsent_w,
                        float* __restrict__ partials, int kbeg_base) {
    int n, tile, kbeg;
    if (MODE == 1) {
        int g = blockIdx.x;               // 0..1151
        int xcd = g & 7, local = g >> 3;
        n = xcd * 4 + local / 36;         // 4 consecutive n per XCD
        tile = local % 36;
        kbeg = 0;
    } else {                              // MODE 2: enc split-K
        n = 0;
        tile = blockIdx.x >> 2;
        kbeg = (blockIdx.x & 3) * NIT;
        (void)kbeg_base;
    }
    int idx = tile, ti = 0;
    while (idx >= 8 - ti) { idx -= 8 - ti; ti++; }
    int tj = ti + idx;
    const unsigned short* Xn = Xb + (size_t)n * BDIM * DDIM;
    const float* sqn = sqv + n * BDIM;
    int i0 = ti * 128, j0 = tj * 128;
    bool diag = (ti == tj);

    __shared__ __align__(16) unsigned short Ash[3][4096];   // 3 x 8KB
    __shared__ __align__(16) unsigned short Bsh[3][4096];
    __shared__ float red[4];

    int t = threadIdx.x, wid = t >> 6, l = t & 63;
    int wr = wid >> 1, wc = wid & 1;
    bool dead = diag && (wr > wc);
    int cg = l >> 4, lr = l & 15;

    f32x4 acc[4][4];
    #pragma unroll
    for (int a = 0; a < 4; a++)
        #pragma unroll
        for (int c = 0; c < 4; c++) acc[a][c] = f32x4{0.f, 0.f, 0.f, 0.f};

    int eoffA[4], eoffB[4];
    #pragma unroll
    for (int f = 0; f < 4; f++) {
        int ra = wr * 64 + f * 16 + lr;
        eoffA[f] = ra * 32 + ((cg ^ ((ra >> 1) & 3)) * 8);
        int rb = wc * 64 + f * 16 + lr;
        eoffB[f] = rb * 32 + ((cg ^ ((rb >> 1) & 3)) * 8);
    }

    int rs = wid * 16 + (l >> 2);
    int cgs = (l & 3) ^ ((rs >> 1) & 3);
    const unsigned short* gA0 = Xn + (size_t)(i0 + rs) * DDIM + cgs * 8;
    const unsigned short* gA1 = gA0 + (size_t)64 * DDIM;
    const unsigned short* gB0 = Xn + (size_t)(j0 + rs) * DDIM + cgs * 8;
    const unsigned short* gB1 = gB0 + (size_t)64 * DDIM;

    auto stage = [&](int buf, int kt) {
        int ko = kt * 32;
        gload16(gA0 + ko, &Ash[buf][wid * 512]);
        gload16(gA1 + ko, &Ash[buf][2048 + wid * 512]);
        gload16(gB0 + ko, &Bsh[buf][wid * 512]);
        gload16(gB1 + ko, &Bsh[buf][2048 + wid * 512]);
    };
    auto compute = [&](int buf) {
        if (dead) return;
        bf16x8 af[4], bfr[4];
        #pragma unroll
        for (int f = 0; f < 4; f++) {
            af[f]  = *(const bf16x8*)&Ash[buf][eoffA[f]];
            bfr[f] = *(const bf16x8*)&Bsh[buf][eoffB[f]];
        }
        #pragma unroll
        for (int fi = 0; fi < 4; fi++)
            #pragma unroll
            for (int fj = 0; fj < 4; fj++) {
                if (diag && wr == wc && fj < fi) continue;
                acc[fi][fj] = mfma16(af[fi], bfr[fj], acc[fi][fj]);
            }
    };

    int klast = kbeg + NIT - 1;
#define GSTEP(SB, CB) do {                       \
        int nx = c + 1; if (nx > klast) nx = klast; \
        stage(SB, nx);                           \
        WAITVM(4);                               \
        bar();                                   \
        compute(CB);                             \
        ++c; } while (0)

    stage(0, kbeg);
    int c = kbeg;
    #pragma unroll 1
    for (int it = 0; it < NIT / 3; ++it) {
        GSTEP(1, 0);
        GSTEP(2, 1);
        GSTEP(0, 2);
    }
    if (NIT % 3 >= 1) GSTEP(1, 0);
    if (NIT % 3 >= 2) GSTEP(2, 1);
#undef GSTEP
    asm volatile("s_waitcnt vmcnt(0)" ::: "memory");   // drain stale DMA before exit

    float lsum = 0.f;
    if (!dead) {
        #pragma unroll
        for (int fi = 0; fi < 4; fi++) {
            #pragma unroll
            for (int fj = 0; fj < 4; fj++) {
                if (diag && wr == wc && fj < fi) continue;
                int jg = j0 + wc * 64 + fj * 16 + lr;
                #pragma unroll
                for (int e = 0; e < 4; e++) {
                    int ig = i0 + wr * 64 + fi * 16 + cg * 4 + e;
                    float g = acc[fi][fj][e];
                    if (MODE == 2) {
                        atomicAdd(&dsent_w[(size_t)ig * BDIM + jg], g);
                    } else {
                        float d2 = sqn[ig] + sqn[jg] - 2.f * g;
                        float d = sqrtf(fmaxf(d2, 0.f) + 1e-12f);
                        if (!diag || jg > ig) {
                            float diff = d - dsent_r[(size_t)ig * BDIM + jg];
                            lsum += diff * diff;
                        }
                    }
                }
            }
        }
    }
    if (MODE == 1) {
        lsum = wave_sum(lsum * 2.f);             // strict upper counted twice
        if (l == 0) red[wid] = lsum;
        __syncthreads();
        if (t == 0) partials[blockIdx.x] = red[0] + red[1] + red[2] + red[3];
    }
}

// Batched per-b 32x32 gram, 2-phase dbuf. Per-block partial output.
__global__ void secret4_k(const unsigned short* __restrict__ Xb,
                          const float* __restrict__ sq_out, float* __restrict__ partials) {
    __shared__ __align__(16) unsigned short S[2][32 * 4 * 128];
    __shared__ float red[4];
    int t = threadIdx.x, wid = t >> 6, l = t & 63;
    int b0 = blockIdx.x * 4;
    int cg = l >> 4, lr = l & 15;
    f32x4 a00 = {0.f,0.f,0.f,0.f}, a01 = {0.f,0.f,0.f,0.f}, a11 = {0.f,0.f,0.f,0.f};

    auto stage = [&](int buf, int kt) {
        #pragma unroll
        for (int m = 0; m < 8; ++m) {
            int n = m * 4 + wid;
            gload16(Xb + ((size_t)(n * BDIM + b0 + cg)) * DDIM + kt * 128 + ((lr ^ (n & 7)) * 8),
                    &S[buf][n * 512]);
        }
    };
    auto compute = [&](int buf) {
        #pragma unroll
        for (int k2 = 0; k2 < 4; ++k2) {
            int cs = k2 * 4 + cg;
            int cl = (cs ^ (lr & 7)) * 8;
            bf16x8 u0 = *(const bf16x8*)&S[buf][lr * 512 + wid * 128 + cl];
            bf16x8 u1 = *(const bf16x8*)&S[buf][(16 + lr) * 512 + wid * 128 + cl];
            a00 = mfma16(u0, u0, a00);
            a01 = mfma16(u0, u1, a01);
            a11 = mfma16(u1, u1, a11);
        }
    };

    stage(0, 0);
    __syncthreads();
    for (int kt = 0; kt < 6; kt += 2) {
        stage(1, kt + 1);
        compute(0);
        __syncthreads();
        stage(0, kt + 2);
        compute(1);
        __syncthreads();
    }
    stage(1, 7);
    compute(0);
    __syncthreads();
    compute(1);

    float lsum = 0.f;
    int b = b0 + wid;
    auto proc = [&](const f32x4& acc, int rb, int cb) {
        #pragma unroll
        for (int e = 0; e < 4; e++) {
            int i = rb * 16 + cg * 4 + e;
            int j = cb * 16 + lr;
            if (j > i) {
                float d2 = sq_out[(size_t)i * BDIM + b] + sq_out[(size_t)j * BDIM + b] - 2.f * acc[e];
                float d = sqrtf(fmaxf(d2, 0.f) + 1e-12f);
                lsum += fmaxf(1.f - d, 0.f);
            }
        }
    };
    proc(a00, 0, 0); proc(a01, 0, 1); proc(a11, 1, 1);
    lsum = wave_sum(lsum);
    if (l == 0) red[wid] = lsum;
    __syncthreads();
    if (t == 0) partials[blockIdx.x] = red[0] + red[1] + red[2] + red[3];
}

// Reduce partials (1152 sentence + 256 secret) and write the 3 outputs.
__global__ void fin2_k(const float* __restrict__ ps, const float* __restrict__ psec,
                       float* __restrict__ out) {
    __shared__ float red[16];
    int t = threadIdx.x;
    float s = 0.f;
    for (int i = t; i < 36 * N_SEC; i += 256) s += ps[i];
    float s2 = psec[t];                       // exactly 256 partials
    s = wave_sum(s);
    s2 = wave_sum(s2);
    if ((t & 63) == 0) { red[t >> 6] = s; red[8 + (t >> 6)] = s2; }
    __syncthreads();
    if (t == 0) {
        float a = red[0] + red[1] + red[2] + red[3];
        float b = red[8] + red[9] + red[10] + red[11];
        float sl = a * (1.0f / 33554432.0f);           // / (N*B*B)
        float sec = b * (1.0f / (1024.0f * 496.0f));   // / B / n_pairs
        out[0] = 0.5f * sl + 0.5f * sec;
        out[1] = sl;
        out[2] = sec;
    }
}

// ---------------------------------------------------------------------------
// Path B (fallback, known-good): fp32 reads + in-loop convert.
// ---------------------------------------------------------------------------

__global__ void norms_k(const float* __restrict__ outp, const float* __restrict__ enc,
                        float* __restrict__ sq_out, float* __restrict__ sq_enc) {
    int wid = threadIdx.x >> 6, l = threadIdx.x & 63;
    int r = blockIdx.x * 4 + wid;
    const float* src = (r < N_SEC * BDIM) ? (outp + (size_t)r * DDIM)
                                          : (enc + (size_t)(r - N_SEC * BDIM) * DDIM);
    float s = 0.f;
    #pragma unroll
    for (int q = 0; q < 4; q++) {
        float4 v = reinterpret_cast<const float4*>(src)[l + q * 64];
        unsigned u0 = pk2(v.x, v.y), u1 = pk2(v.z, v.w);
        float a = __uint_as_float(u0 << 16), b = __uint_as_float(u0 & 0xFFFF0000u);
        float c = __uint_as_float(u1 << 16), d = __uint_as_float(u1 & 0xFFFF0000u);
        s += a * a + b * b + c * c + d * d;
    }
    s = wave_sum(s);
    if (l == 0) { if (r < N_SEC * BDIM) sq_out[r] = s; else sq_enc[r - N_SEC * BDIM] = s; }
}

template<int MODE>
__global__ void gram_k(const float* __restrict__ X, const float* __restrict__ sqv,
                       const float* __restrict__ dsent_r, float* __restrict__ dsent_w,
                       float* __restrict__ accum) {
    int idx = blockIdx.x, ti = 0;
    while (idx >= 8 - ti) { idx -= 8 - ti; ti++; }
    int tj = ti + idx;
    int n = (MODE == 1) ? blockIdx.y : 0;
    const float* Xn = X + (size_t)n * BDIM * DDIM;
    const float* sqn = sqv + n * BDIM;
    int i0 = ti * 128, j0 = tj * 128;
    bool diag = (ti == tj);
    __shared__ __align__(16) unsigned short Ash[128 * 32];
    __shared__ __align__(16) unsigned short Bsh[128 * 32];
    int t = threadIdx.x, wid = t >> 6, l = t & 63;
    int wr = wid >> 1, wc = wid & 1;
    bool dead = diag && (wr > wc);
    int cg = l >> 4, lr = l & 15;
    f32x4 acc[4][4];
    #pragma unroll
    for (int a = 0; a < 4; a++)
        #pragma unroll
        for (int c = 0; c < 4; c++) acc[a][c] = f32x4{0.f, 0.f, 0.f, 0.f};
    int r0 = t >> 2, c0 = t & 3;
    int swz0 = (c0 ^ (r0 & 3)) * 8;
    int off0 = r0 * 32 + swz0;
    int off1 = (r0 + 64) * 32 + swz0;
    for (int kt = 0; kt < DDIM / 32; ++kt) {
        int k0 = kt * 32;
        const float4* pa0 = (const float4*)(Xn + (size_t)(i0 + r0) * DDIM + k0 + c0 * 8);
        const float4* pa1 = (const float4*)(Xn + (size_t)(i0 + r0 + 64) * DDIM + k0 + c0 * 8);
        const float4* pb0 = (const float4*)(Xn + (size_t)(j0 + r0) * DDIM + k0 + c0 * 8);
        const float4* pb1 = (const float4*)(Xn + (size_t)(j0 + r0 + 64) * DDIM + k0 + c0 * 8);
        float4 a00 = pa0[0], a01 = pa0[1];
        float4 a10 = pa1[0], a11 = pa1[1];
        float4 b00 = pb0[0], b01 = pb0[1];
        float4 b10 = pb1[0], b11 = pb1[1];
        __syncthreads();
        *(i32x4*)&Ash[off0] = pack8(a00, a01);
        *(i32x4*)&Ash[off1] = pack8(a10, a11);
        *(i32x4*)&Bsh[off0] = pack8(b00, b01);
        *(i32x4*)&Bsh[off1] = pack8(b10, b11);
        __syncthreads();
        if (!dead) {
            bf16x8 af[4], bfr[4];
            #pragma unroll
            for (int f = 0; f < 4; f++) {
                int ra = wr * 64 + f * 16 + lr;
                af[f] = *(const bf16x8*)&Ash[ra * 32 + ((cg ^ (ra & 3)) * 8)];
                int rb = wc * 64 + f * 16 + lr;
                bfr[f] = *(const bf16x8*)&Bsh[rb * 32 + ((cg ^ (rb & 3)) * 8)];
            }
            #pragma unroll
            for (int fi = 0; fi < 4; fi++)
                #pragma unroll
                for (int fj = 0; fj < 4; fj++) {
                    if (diag && wr == wc && fj < fi) continue;
                    acc[fi][fj] = mfma16(af[fi], bfr[fj], acc[fi][fj]);
                }
        }
    }
    if (!dead) {
        float lsum = 0.f;
        #pragma unroll
        for (int fi = 0; fi < 4; fi++) {
            #pragma unroll
            for (int fj = 0; fj < 4; fj++) {
                if (diag && wr == wc && fj < fi) continue;
                int jg = j0 + wc * 64 + fj * 16 + lr;
                #pragma unroll
                for (int e = 0; e < 4; e++) {
                    int ig = i0 + wr * 64 + fi * 16 + cg * 4 + e;
                    float g = acc[fi][fj][e];
                    float d2 = sqn[ig] + sqn[jg] - 2.f * g;
                    float d = sqrtf(fmaxf(d2, 0.f) + 1e-12f);
                    if (MODE == 0) {
                        dsent_w[(size_t)ig * BDIM + jg] = d;
                    } else {
                        if (!diag || jg > ig) {
                            float diff = d - dsent_r[(size_t)ig * BDIM + jg];
                            lsum += diff * diff;
                        }
                    }
                }
            }
        }
        if (MODE == 1) {
            lsum = wave_sum(lsum * 2.f);
            if (l == 0) atomicAdd(accum, lsum);
        }
    }
}

__global__ void secret_k(const float* __restrict__ X, const float* __restrict__ sq_out,
                         float* __restrict__ accum) {
    int wid = threadIdx.x >> 6, l = threadIdx.x & 63;
    int b = blockIdx.x * 4 + wid;
    int cg = l >> 4, lr = l & 15;
    f32x4 a00 = {0.f,0.f,0.f,0.f}, a01 = {0.f,0.f,0.f,0.f}, a11 = {0.f,0.f,0.f,0.f};
    for (int kt = 0; kt < 32; ++kt) {
        int k0 = kt * 32 + cg * 8;
        const float4* p0 = (const float4*)(X + ((size_t)lr * BDIM + b) * DDIM + k0);
        const float4* p1 = (const float4*)(X + ((size_t)(16 + lr) * BDIM + b) * DDIM + k0);
        union { i32x4 i; bf16x8 s; } u0, u1;
        u0.i = pack8(p0[0], p0[1]);
        u1.i = pack8(p1[0], p1[1]);
        a00 = mfma16(u0.s, u0.s, a00);
        a01 = mfma16(u0.s, u1.s, a01);
        a11 = mfma16(u1.s, u1.s, a11);
    }
    float lsum = 0.f;
    auto proc = [&](const f32x4& acc, int rb, int cb) {
        #pragma unroll
        for (int e = 0; e < 4; e++) {
            int i = rb * 16 + cg * 4 + e;
            int j = cb * 16 + lr;
            if (j > i) {
                float d2 = sq_out[(size_t)i * BDIM + b] + sq_out[(size_t)j * BDIM + b] - 2.f * acc[e];
                float d = sqrtf(fmaxf(d2, 0.f) + 1e-12f);
                lsum += fmaxf(1.f - d, 0.f);
            }
        }
    };
    proc(a00, 0, 0); proc(a01, 0, 1); proc(a11, 1, 1);
    lsum = wave_sum(lsum);
    if (l == 0) atomicAdd(accum, lsum);
}

__global__ void init_k(float* sums) { sums[threadIdx.x] = 0.f; }

__global__ void fin_k(const float* __restrict__ sums, float* __restrict__ out) {
    float sl = sums[0] * (1.0f / 33554432.0f);
    float sec = sums[1] * (1.0f / (1024.0f * 496.0f));
    out[0] = 0.5f * sl + 0.5f * sec;
    out[1] = sl;
    out[2] = sec;
}

extern "C" void kernel_launch(void* const* d_in, const int* in_sizes, int n_in,
                              void* d_out, int out_size, void* d_ws, size_t ws_size,
                              hipStream_t stream) {
    const float* outputs = (const float*)d_in[0];   // [32,1024,1024] f32
    const float* enc     = (const float*)d_in[1];   // [1024,1024] f32
    float* out = (float*)d_out;                     // 3 floats

    float* ps     = (float*)d_ws;
    float* psec   = ps + 1536;
    float* sq_out = ps + 2048;
    float* sq_enc = sq_out + N_SEC * BDIM;
    float* dsent  = sq_enc + BDIM;
    unsigned short* Xbf = (unsigned short*)(dsent + (size_t)BDIM * BDIM);
    unsigned short* Ebf = Xbf + (size_t)N_SEC * BDIM * DDIM;

    const size_t NEED = 4 * (2048 + (size_t)N_SEC * BDIM + BDIM + (size_t)BDIM * BDIM)
                      + 2 * ((size_t)N_SEC * BDIM * DDIM + (size_t)BDIM * DDIM);

    if (ws_size >= NEED) {
        hipLaunchKernelGGL(prep_k, dim3((N_SEC * BDIM + BDIM) / 4), dim3(256), 0, stream,
                           outputs, enc, Xbf, Ebf, sq_out, sq_enc);
        hipLaunchKernelGGL(zero_k, dim3(512), dim3(256), 0, stream, dsent);
        hipLaunchKernelGGL((gram8_k<2, 8>), dim3(36 * 4), dim3(256), 0, stream,
                           Ebf, sq_enc, (const float*)nullptr, dsent, (float*)nullptr, 0);
        hipLaunchKernelGGL(cvt0_k, dim3(512), dim3(256), 0, stream, dsent, sq_enc);
        hipLaunchKernelGGL((gram8_k<1, 32>), dim3(36 * N_SEC), dim3(256), 0, stream,
                           Xbf, sq_out, (const float*)dsent, (float*)nullptr, ps, 0);
        hipLaunchKernelGGL(secret4_k, dim3(BDIM / 4), dim3(256), 0, stream,
                           Xbf, sq_out, psec);
        hipLaunchKernelGGL(fin2_k, dim3(1), dim3(256), 0, stream, ps, psec, out);
    } else {
        float* sums = (float*)d_ws;
        float* fsq_out = sums + 64;
        float* fsq_enc = fsq_out + N_SEC * BDIM;
        float* fdsent  = fsq_enc + BDIM;
        hipLaunchKernelGGL(init_k, dim3(1), dim3(2), 0, stream, sums);
        hipLaunchKernelGGL(norms_k, dim3((N_SEC * BDIM + BDIM) / 4), dim3(256), 0, stream,
                           outputs, enc, fsq_out, fsq_enc);
        hipLaunchKernelGGL((gram_k<0>), dim3(36), dim3(256), 0, stream,
                           enc, fsq_enc, (const float*)nullptr, fdsent, (float*)nullptr);
        hipLaunchKernelGGL((gram_k<1>), dim3(36, N_SEC), dim3(256), 0, stream,
                           outputs, fsq_out, (const float*)fdsent, (float*)nullptr, &sums[0]);
        hipLaunchKernelGGL(secret_k, dim3(BDIM / 4), dim3(256), 0, stream,
                           outputs, fsq_out, &sums[1]);
        hipLaunchKernelGGL(fin_k, dim3(1), dim3(1), 0, stream, sums, out);
    }
}

// Round 14
// 145.296 us; speedup vs baseline: 1.1121x; 1.0126x over previous
//
#include <hip/hip_runtime.h>
#include <hip/hip_bf16.h>

#define N_SEC 32
#define BDIM 1024
#define DDIM 1024

typedef __attribute__((ext_vector_type(8))) short bf16x8;
typedef __attribute__((ext_vector_type(4))) float f32x4;
typedef __attribute__((ext_vector_type(4))) int i32x4;

#define WAITVM(n) asm volatile("s_waitcnt vmcnt(" #n ")" ::: "memory")

__device__ __forceinline__ void bar() {           // raw barrier + compiler fence
    __builtin_amdgcn_s_barrier();                 // (NO sched_barrier - m141)
    asm volatile("" ::: "memory");
}

__device__ __forceinline__ unsigned pk2(float a, float b) {
    union { __hip_bfloat162 h; unsigned u; } cv;
    cv.h = __float22bfloat162_rn(make_float2(a, b));
    return cv.u;
}

__device__ __forceinline__ i32x4 pack8(float4 a, float4 b) {
    i32x4 r;
    r[0] = pk2(a.x, a.y); r[1] = pk2(a.z, a.w);
    r[2] = pk2(b.x, b.y); r[3] = pk2(b.z, b.w);
    return r;
}

__device__ __forceinline__ f32x4 mfma16(bf16x8 a, bf16x8 b, f32x4 c) {
    return __builtin_amdgcn_mfma_f32_16x16x32_bf16(a, b, c, 0, 0, 0);
}

__device__ __forceinline__ float wave_sum(float v) {
    #pragma unroll
    for (int off = 32; off > 0; off >>= 1) v += __shfl_down(v, off, 64);
    return v;
}

__device__ __forceinline__ void gload16(const unsigned short* g, unsigned short* l) {
    __builtin_amdgcn_global_load_lds(
        (const __attribute__((address_space(1))) unsigned int*)g,
        (__attribute__((address_space(3))) unsigned int*)l, 16, 0, 0);
}

// ---------------------------------------------------------------------------
// Path A: prep, zero, gram8<2> (enc split-K, atomic gram), cvt0,
// gramF (2-buffer double-light-barrier, 32KB LDS), secret4, fin2.
// ---------------------------------------------------------------------------

__global__ void prep_k(const float* __restrict__ outp, const float* __restrict__ enc,
                       unsigned short* __restrict__ Xb, unsigned short* __restrict__ Eb,
                       float* __restrict__ sq_out, float* __restrict__ sq_enc) {
    int wid = threadIdx.x >> 6, l = threadIdx.x & 63;
    int r = blockIdx.x * 4 + wid;
    bool isOut = r < N_SEC * BDIM;
    const float* src = isOut ? (outp + (size_t)r * DDIM)
                             : (enc + (size_t)(r - N_SEC * BDIM) * DDIM);
    unsigned short* dst = isOut ? (Xb + (size_t)r * DDIM)
                                : (Eb + (size_t)(r - N_SEC * BDIM) * DDIM);
    const float4* s4 = (const float4*)src;
    float s = 0.f;
    #pragma unroll
    for (int h = 0; h < 2; ++h) {
        int c = l + h * 64;
        float4 v0 = s4[2 * c], v1 = s4[2 * c + 1];
        i32x4 p = pack8(v0, v1);
        *(i32x4*)&dst[c * 8] = p;
        #pragma unroll
        for (int e = 0; e < 4; ++e) {
            unsigned u = (unsigned)p[e];
            float a = __uint_as_float(u << 16);
            float b = __uint_as_float(u & 0xFFFF0000u);
            s += a * a + b * b;
        }
    }
    s = wave_sum(s);
    if (l == 0) { if (isOut) sq_out[r] = s; else sq_enc[r - N_SEC * BDIM] = s; }
}

__global__ void zero_k(float* __restrict__ p) {
    int i = blockIdx.x * blockDim.x + threadIdx.x;       // 512*256*2 = 256K f4
    float4 z = {0.f, 0.f, 0.f, 0.f};
    ((float4*)p)[i] = z;
    ((float4*)p)[i + 131072] = z;
}

// In-place: g -> sqrt(max(sq[i]+sq[j]-2g,0)+eps) over the 1024x1024 plane.
__global__ void cvt0_k(float* __restrict__ d, const float* __restrict__ sq) {
    int t = blockIdx.x * blockDim.x + threadIdx.x;       // 512 blocks * 256
    #pragma unroll
    for (int h = 0; h < 2; ++h) {
        int idx = t + h * 131072;                        // float4 index
        int i = idx >> 8;                                // (idx*4)>>10
        float si = sq[i];
        float4 g = ((const float4*)d)[idx];
        int j0 = (idx & 255) * 4;
        float4 r;
        r.x = sqrtf(fmaxf(si + sq[j0 + 0] - 2.f * g.x, 0.f) + 1e-12f);
        r.y = sqrtf(fmaxf(si + sq[j0 + 1] - 2.f * g.y, 0.f) + 1e-12f);
        r.z = sqrtf(fmaxf(si + sq[j0 + 2] - 2.f * g.z, 0.f) + 1e-12f);
        r.w = sqrtf(fmaxf(si + sq[j0 + 3] - 2.f * g.w, 0.f) + 1e-12f);
        ((float4*)d)[idx] = r;
    }
}

// enc gram, split-K: 36 upper tiles x 4 K-slices, 3-buffer counted-vmcnt.
// MODE 2: K-slice [kbeg,kbeg+NIT), atomicAdd raw gram into dsent_w.
template<int MODE, int NIT>
__global__ void gram8_k(const unsigned short* __restrict__ Xb, const float* __restrict__ sqv,
                        const float* __restrict__ dsent_r, float* __restrict__ dsent_w,
                        float* __restrict__ partials, int kbeg_base) {
    int n, tile, kbeg;
    if (MODE == 1) {
        int g = blockIdx.x;
        int xcd = g & 7, local = g >> 3;
        n = xcd * 4 + local / 36;
        tile = local % 36;
        kbeg = 0;
    } else {
        n = 0;
        tile = blockIdx.x >> 2;
        kbeg = (blockIdx.x & 3) * NIT;
        (void)kbeg_base;
    }
    int idx = tile, ti = 0;
    while (idx >= 8 - ti) { idx -= 8 - ti; ti++; }
    int tj = ti + idx;
    const unsigned short* Xn = Xb + (size_t)n * BDIM * DDIM;
    const float* sqn = sqv + n * BDIM;
    int i0 = ti * 128, j0 = tj * 128;
    bool diag = (ti == tj);

    __shared__ __align__(16) unsigned short Ash[3][4096];   // 3 x 8KB
    __shared__ __align__(16) unsigned short Bsh[3][4096];
    __shared__ float red[4];

    int t = threadIdx.x, wid = t >> 6, l = t & 63;
    int wr = wid >> 1, wc = wid & 1;
    bool dead = diag && (wr > wc);
    int cg = l >> 4, lr = l & 15;

    f32x4 acc[4][4];
    #pragma unroll
    for (int a = 0; a < 4; a++)
        #pragma unroll
        for (int c = 0; c < 4; c++) acc[a][c] = f32x4{0.f, 0.f, 0.f, 0.f};

    int eoffA[4], eoffB[4];
    #pragma unroll
    for (int f = 0; f < 4; f++) {
        int ra = wr * 64 + f * 16 + lr;
        eoffA[f] = ra * 32 + ((cg ^ ((ra >> 1) & 3)) * 8);
        int rb = wc * 64 + f * 16 + lr;
        eoffB[f] = rb * 32 + ((cg ^ ((rb >> 1) & 3)) * 8);
    }

    int rs = wid * 16 + (l >> 2);
    int cgs = (l & 3) ^ ((rs >> 1) & 3);
    const unsigned short* gA0 = Xn + (size_t)(i0 + rs) * DDIM + cgs * 8;
    const unsigned short* gA1 = gA0 + (size_t)64 * DDIM;
    const unsigned short* gB0 = Xn + (size_t)(j0 + rs) * DDIM + cgs * 8;
    const unsigned short* gB1 = gB0 + (size_t)64 * DDIM;

    auto stage = [&](int buf, int kt) {
        int ko = kt * 32;
        gload16(gA0 + ko, &Ash[buf][wid * 512]);
        gload16(gA1 + ko, &Ash[buf][2048 + wid * 512]);
        gload16(gB0 + ko, &Bsh[buf][wid * 512]);
        gload16(gB1 + ko, &Bsh[buf][2048 + wid * 512]);
    };
    auto compute = [&](int buf) {
        if (dead) return;
        bf16x8 af[4], bfr[4];
        #pragma unroll
        for (int f = 0; f < 4; f++) {
            af[f]  = *(const bf16x8*)&Ash[buf][eoffA[f]];
            bfr[f] = *(const bf16x8*)&Bsh[buf][eoffB[f]];
        }
        #pragma unroll
        for (int fi = 0; fi < 4; fi++)
            #pragma unroll
            for (int fj = 0; fj < 4; fj++) {
                if (diag && wr == wc && fj < fi) continue;
                acc[fi][fj] = mfma16(af[fi], bfr[fj], acc[fi][fj]);
            }
    };

    int klast = kbeg + NIT - 1;
#define GSTEP(SB, CB) do {                       \
        int nx = c + 1; if (nx > klast) nx = klast; \
        stage(SB, nx);                           \
        WAITVM(4);                               \
        bar();                                   \
        compute(CB);                             \
        ++c; } while (0)

    stage(0, kbeg);
    int c = kbeg;
    #pragma unroll 1
    for (int it = 0; it < NIT / 3; ++it) {
        GSTEP(1, 0);
        GSTEP(2, 1);
        GSTEP(0, 2);
    }
    if (NIT % 3 >= 1) GSTEP(1, 0);
    if (NIT % 3 >= 2) GSTEP(2, 1);
#undef GSTEP
    asm volatile("s_waitcnt vmcnt(0)" ::: "memory");

    float lsum = 0.f;
    if (!dead) {
        #pragma unroll
        for (int fi = 0; fi < 4; fi++) {
            #pragma unroll
            for (int fj = 0; fj < 4; fj++) {
                if (diag && wr == wc && fj < fi) continue;
                int jg = j0 + wc * 64 + fj * 16 + lr;
                #pragma unroll
                for (int e = 0; e < 4; e++) {
                    int ig = i0 + wr * 64 + fi * 16 + cg * 4 + e;
                    float g = acc[fi][fj][e];
                    if (MODE == 2) {
                        atomicAdd(&dsent_w[(size_t)ig * BDIM + jg], g);
                    } else {
                        float d2 = sqn[ig] + sqn[jg] - 2.f * g;
                        float d = sqrtf(fmaxf(d2, 0.f) + 1e-12f);
                        if (!diag || jg > ig) {
                            float diff = d - dsent_r[(size_t)ig * BDIM + jg];
                            lsum += diff * diff;
                        }
                    }
                }
            }
        }
    }
    if (MODE == 1) {
        lsum = wave_sum(lsum * 2.f);
        if (l == 0) red[wid] = lsum;
        __syncthreads();
        if (t == 0) partials[blockIdx.x] = red[0] + red[1] + red[2] + red[3];
    }
}

// Main gram (R11 fused_k gram path, standalone): 128^2 triangle tile, 4 waves,
// BK=32, 2-buffer (32KB LDS -> 4+ blk/CU), double-light-barrier:
//   {bar1; stage(kt+1 -> buf^1); vmcnt(4); bar2; compute(kt)}
// Overwrite-safe: victim last read before bar1. Publish-safe: every wave
// retires its own tile-kt loads (vmcnt(4)) before bar2.
__global__ void gramF_k(const unsigned short* __restrict__ Xb,
                        const float* __restrict__ sq_out,
                        const float* __restrict__ dsent,
                        float* __restrict__ ps) {
    __shared__ __align__(16) unsigned short SH[16384];   // 32 KB
    __shared__ float red[4];
    int t = threadIdx.x, wid = t >> 6, l = t & 63;
    int cg = l >> 4, lr = l & 15;

    int g = blockIdx.x;                       // 0..1151
    int xcd = g & 7, local = g >> 3;
    int n = xcd * 4 + local / 36;             // 4 consecutive n per XCD
    int tile = local % 36;
    int idx = tile, ti = 0;
    while (idx >= 8 - ti) { idx -= 8 - ti; ti++; }
    int tj = ti + idx;
    const unsigned short* Xn = Xb + (size_t)n * BDIM * DDIM;
    const float* sqn = sq_out + n * BDIM;
    int i0 = ti * 128, j0 = tj * 128;
    bool diag = (ti == tj);

    int wr = wid >> 1, wc = wid & 1;
    bool dead = diag && (wr > wc);

    f32x4 acc[4][4];
    #pragma unroll
    for (int a = 0; a < 4; a++)
        #pragma unroll
        for (int c = 0; c < 4; c++) acc[a][c] = f32x4{0.f, 0.f, 0.f, 0.f};

    int eoffA[4], eoffB[4];
    #pragma unroll
    for (int f = 0; f < 4; f++) {
        int ra = wr * 64 + f * 16 + lr;
        eoffA[f] = ra * 32 + ((cg ^ ((ra >> 1) & 3)) * 8);
        int rb = wc * 64 + f * 16 + lr;
        eoffB[f] = rb * 32 + ((cg ^ ((rb >> 1) & 3)) * 8);
    }

    int rs = wid * 16 + (l >> 2);
    int cgs = (l & 3) ^ ((rs >> 1) & 3);
    const unsigned short* gA0 = Xn + (size_t)(i0 + rs) * DDIM + cgs * 8;
    const unsigned short* gA1 = gA0 + (size_t)64 * DDIM;
    const unsigned short* gB0 = Xn + (size_t)(j0 + rs) * DDIM + cgs * 8;
    const unsigned short* gB1 = gB0 + (size_t)64 * DDIM;

    auto stage = [&](int buf, int kt) {       // 4 VMEM ops per thread
        int ko = kt * 32;
        gload16(gA0 + ko, &SH[buf * 4096 + wid * 512]);
        gload16(gA1 + ko, &SH[buf * 4096 + 2048 + wid * 512]);
        gload16(gB0 + ko, &SH[8192 + buf * 4096 + wid * 512]);
        gload16(gB1 + ko, &SH[8192 + buf * 4096 + 2048 + wid * 512]);
    };
    auto compute = [&](int buf) {
        if (dead) return;
        bf16x8 af[4], bfr[4];
        #pragma unroll
        for (int f = 0; f < 4; f++) {
            af[f]  = *(const bf16x8*)&SH[buf * 4096 + eoffA[f]];
            bfr[f] = *(const bf16x8*)&SH[8192 + buf * 4096 + eoffB[f]];
        }
        #pragma unroll
        for (int fi = 0; fi < 4; fi++)
            #pragma unroll
            for (int fj = 0; fj < 4; fj++) {
                if (diag && wr == wc && fj < fi) continue;
                acc[fi][fj] = mfma16(af[fi], bfr[fj], acc[fi][fj]);
            }
    };

#define GSTEP(NB, CB) do {                       \
        bar();                                   \
        int nx = c + 1; if (nx > 31) nx = 31;    \
        stage(NB, nx);                           \
        WAITVM(4);                               \
        bar();                                   \
        compute(CB);                             \
        ++c; } while (0)

    stage(0, 0);
    int c = 0;
    #pragma unroll 1
    for (int it = 0; it < 16; ++it) {            // 32 computes, tiles 0..31
        GSTEP(1, 0);
        GSTEP(0, 1);
    }
#undef GSTEP
    asm volatile("s_waitcnt vmcnt(0)" ::: "memory");   // drain before exit

    float lsum = 0.f;
    if (!dead) {
        #pragma unroll
        for (int fi = 0; fi < 4; fi++) {
            #pragma unroll
            for (int fj = 0; fj < 4; fj++) {
                if (diag && wr == wc && fj < fi) continue;
                int jg = j0 + wc * 64 + fj * 16 + lr;
                #pragma unroll
                for (int e = 0; e < 4; e++) {
                    int ig = i0 + wr * 64 + fi * 16 + cg * 4 + e;
                    float gg = acc[fi][fj][e];
                    float d2 = sqn[ig] + sqn[jg] - 2.f * gg;
                    float d = sqrtf(fmaxf(d2, 0.f) + 1e-12f);
                    if (!diag || jg > ig) {
                        float diff = d - dsent[(size_t)ig * BDIM + jg];
                        lsum += diff * diff;
                    }
                }
            }
        }
    }
    lsum = wave_sum(lsum * 2.f);                 // strict upper counted twice
    if (l == 0) red[wid] = lsum;
    __syncthreads();
    if (t == 0) ps[g] = red[0] + red[1] + red[2] + red[3];
}

// Batched per-b 32x32 gram, 2-phase dbuf. Per-block partial output.
__global__ void secret4_k(const unsigned short* __restrict__ Xb,
                          const float* __restrict__ sq_out, float* __restrict__ partials) {
    __shared__ __align__(16) unsigned short S[2][32 * 4 * 128];
    __shared__ float red[4];
    int t = threadIdx.x, wid = t >> 6, l = t & 63;
    int b0 = blockIdx.x * 4;
    int cg = l >> 4, lr = l & 15;
    f32x4 a00 = {0.f,0.f,0.f,0.f}, a01 = {0.f,0.f,0.f,0.f}, a11 = {0.f,0.f,0.f,0.f};

    auto stage = [&](int buf, int kt) {
        #pragma unroll
        for (int m = 0; m < 8; ++m) {
            int n = m * 4 + wid;
            gload16(Xb + ((size_t)(n * BDIM + b0 + cg)) * DDIM + kt * 128 + ((lr ^ (n & 7)) * 8),
                    &S[buf][n * 512]);
        }
    };
    auto compute = [&](int buf) {
        #pragma unroll
        for (int k2 = 0; k2 < 4; ++k2) {
            int cs = k2 * 4 + cg;
            int cl = (cs ^ (lr & 7)) * 8;
            bf16x8 u0 = *(const bf16x8*)&S[buf][lr * 512 + wid * 128 + cl];
            bf16x8 u1 = *(const bf16x8*)&S[buf][(16 + lr) * 512 + wid * 128 + cl];
            a00 = mfma16(u0, u0, a00);
            a01 = mfma16(u0, u1, a01);
            a11 = mfma16(u1, u1, a11);
        }
    };

    stage(0, 0);
    __syncthreads();
    for (int kt = 0; kt < 6; kt += 2) {
        stage(1, kt + 1);
        compute(0);
        __syncthreads();
        stage(0, kt + 2);
        compute(1);
        __syncthreads();
    }
    stage(1, 7);
    compute(0);
    __syncthreads();
    compute(1);

    float lsum = 0.f;
    int b = b0 + wid;
    auto proc = [&](const f32x4& acc, int rb, int cb) {
        #pragma unroll
        for (int e = 0; e < 4; e++) {
            int i = rb * 16 + cg * 4 + e;
            int j = cb * 16 + lr;
            if (j > i) {
                float d2 = sq_out[(size_t)i * BDIM + b] + sq_out[(size_t)j * BDIM + b] - 2.f * acc[e];
                float d = sqrtf(fmaxf(d2, 0.f) + 1e-12f);
                lsum += fmaxf(1.f - d, 0.f);
            }
        }
    };
    proc(a00, 0, 0); proc(a01, 0, 1); proc(a11, 1, 1);
    lsum = wave_sum(lsum);
    if (l == 0) red[wid] = lsum;
    __syncthreads();
    if (t == 0) partials[blockIdx.x] = red[0] + red[1] + red[2] + red[3];
}

// Reduce partials (1152 sentence + 256 secret) and write the 3 outputs.
__global__ void fin2_k(const float* __restrict__ ps, const float* __restrict__ psec,
                       float* __restrict__ out) {
    __shared__ float red[16];
    int t = threadIdx.x;
    float s = 0.f;
    for (int i = t; i < 36 * N_SEC; i += 256) s += ps[i];
    float s2 = psec[t];
    s = wave_sum(s);
    s2 = wave_sum(s2);
    if ((t & 63) == 0) { red[t >> 6] = s; red[8 + (t >> 6)] = s2; }
    __syncthreads();
    if (t == 0) {
        float a = red[0] + red[1] + red[2] + red[3];
        float b = red[8] + red[9] + red[10] + red[11];
        float sl = a * (1.0f / 33554432.0f);           // / (N*B*B)
        float sec = b * (1.0f / (1024.0f * 496.0f));   // / B / n_pairs
        out[0] = 0.5f * sl + 0.5f * sec;
        out[1] = sl;
        out[2] = sec;
    }
}

// ---------------------------------------------------------------------------
// Path B (fallback, known-good): fp32 reads + in-loop convert.
// ---------------------------------------------------------------------------

__global__ void norms_k(const float* __restrict__ outp, const float* __restrict__ enc,
                        float* __restrict__ sq_out, float* __restrict__ sq_enc) {
    int wid = threadIdx.x >> 6, l = threadIdx.x & 63;
    int r = blockIdx.x * 4 + wid;
    const float* src = (r < N_SEC * BDIM) ? (outp + (size_t)r * DDIM)
                                          : (enc + (size_t)(r - N_SEC * BDIM) * DDIM);
    float s = 0.f;
    #pragma unroll
    for (int q = 0; q < 4; q++) {
        float4 v = reinterpret_cast<const float4*>(src)[l + q * 64];
        unsigned u0 = pk2(v.x, v.y), u1 = pk2(v.z, v.w);
        float a = __uint_as_float(u0 << 16), b = __uint_as_float(u0 & 0xFFFF0000u);
        float c = __uint_as_float(u1 << 16), d = __uint_as_float(u1 & 0xFFFF0000u);
        s += a * a + b * b + c * c + d * d;
    }
    s = wave_sum(s);
    if (l == 0) { if (r < N_SEC * BDIM) sq_out[r] = s; else sq_enc[r - N_SEC * BDIM] = s; }
}

template<int MODE>
__global__ void gram_k(const float* __restrict__ X, const float* __restrict__ sqv,
                       const float* __restrict__ dsent_r, float* __restrict__ dsent_w,
                       float* __restrict__ accum) {
    int idx = blockIdx.x, ti = 0;
    while (idx >= 8 - ti) { idx -= 8 - ti; ti++; }
    int tj = ti + idx;
    int n = (MODE == 1) ? blockIdx.y : 0;
    const float* Xn = X + (size_t)n * BDIM * DDIM;
    const float* sqn = sqv + n * BDIM;
    int i0 = ti * 128, j0 = tj * 128;
    bool diag = (ti == tj);
    __shared__ __align__(16) unsigned short Ash[128 * 32];
    __shared__ __align__(16) unsigned short Bsh[128 * 32];
    int t = threadIdx.x, wid = t >> 6, l = t & 63;
    int wr = wid >> 1, wc = wid & 1;
    bool dead = diag && (wr > wc);
    int cg = l >> 4, lr = l & 15;
    f32x4 acc[4][4];
    #pragma unroll
    for (int a = 0; a < 4; a++)
        #pragma unroll
        for (int c = 0; c < 4; c++) acc[a][c] = f32x4{0.f, 0.f, 0.f, 0.f};
    int r0 = t >> 2, c0 = t & 3;
    int swz0 = (c0 ^ (r0 & 3)) * 8;
    int off0 = r0 * 32 + swz0;
    int off1 = (r0 + 64) * 32 + swz0;
    for (int kt = 0; kt < DDIM / 32; ++kt) {
        int k0 = kt * 32;
        const float4* pa0 = (const float4*)(Xn + (size_t)(i0 + r0) * DDIM + k0 + c0 * 8);
        const float4* pa1 = (const float4*)(Xn + (size_t)(i0 + r0 + 64) * DDIM + k0 + c0 * 8);
        const float4* pb0 = (const float4*)(Xn + (size_t)(j0 + r0) * DDIM + k0 + c0 * 8);
        const float4* pb1 = (const float4*)(Xn + (size_t)(j0 + r0 + 64) * DDIM + k0 + c0 * 8);
        float4 a00 = pa0[0], a01 = pa0[1];
        float4 a10 = pa1[0], a11 = pa1[1];
        float4 b00 = pb0[0], b01 = pb0[1];
        float4 b10 = pb1[0], b11 = pb1[1];
        __syncthreads();
        *(i32x4*)&Ash[off0] = pack8(a00, a01);
        *(i32x4*)&Ash[off1] = pack8(a10, a11);
        *(i32x4*)&Bsh[off0] = pack8(b00, b01);
        *(i32x4*)&Bsh[off1] = pack8(b10, b11);
        __syncthreads();
        if (!dead) {
            bf16x8 af[4], bfr[4];
            #pragma unroll
            for (int f = 0; f < 4; f++) {
                int ra = wr * 64 + f * 16 + lr;
                af[f] = *(const bf16x8*)&Ash[ra * 32 + ((cg ^ (ra & 3)) * 8)];
                int rb = wc * 64 + f * 16 + lr;
                bfr[f] = *(const bf16x8*)&Bsh[rb * 32 + ((cg ^ (rb & 3)) * 8)];
            }
            #pragma unroll
            for (int fi = 0; fi < 4; fi++)
                #pragma unroll
                for (int fj = 0; fj < 4; fj++) {
                    if (diag && wr == wc && fj < fi) continue;
                    acc[fi][fj] = mfma16(af[fi], bfr[fj], acc[fi][fj]);
                }
        }
    }
    if (!dead) {
        float lsum = 0.f;
        #pragma unroll
        for (int fi = 0; fi < 4; fi++) {
            #pragma unroll
            for (int fj = 0; fj < 4; fj++) {
                if (diag && wr == wc && fj < fi) continue;
                int jg = j0 + wc * 64 + fj * 16 + lr;
                #pragma unroll
                for (int e = 0; e < 4; e++) {
                    int ig = i0 + wr * 64 + fi * 16 + cg * 4 + e;
                    float g = acc[fi][fj][e];
                    float d2 = sqn[ig] + sqn[jg] - 2.f * g;
                    float d = sqrtf(fmaxf(d2, 0.f) + 1e-12f);
                    if (MODE == 0) {
                        dsent_w[(size_t)ig * BDIM + jg] = d;
                    } else {
                        if (!diag || jg > ig) {
                            float diff = d - dsent_r[(size_t)ig * BDIM + jg];
                            lsum += diff * diff;
                        }
                    }
                }
            }
        }
        if (MODE == 1) {
            lsum = wave_sum(lsum * 2.f);
            if (l == 0) atomicAdd(accum, lsum);
        }
    }
}

__global__ void secret_k(const float* __restrict__ X, const float* __restrict__ sq_out,
                         float* __restrict__ accum) {
    int wid = threadIdx.x >> 6, l = threadIdx.x & 63;
    int b = blockIdx.x * 4 + wid;
    int cg = l >> 4, lr = l & 15;
    f32x4 a00 = {0.f,0.f,0.f,0.f}, a01 = {0.f,0.f,0.f,0.f}, a11 = {0.f,0.f,0.f,0.f};
    for (int kt = 0; kt < 32; ++kt) {
        int k0 = kt * 32 + cg * 8;
        const float4* p0 = (const float4*)(X + ((size_t)lr * BDIM + b) * DDIM + k0);
        const float4* p1 = (const float4*)(X + ((size_t)(16 + lr) * BDIM + b) * DDIM + k0);
        union { i32x4 i; bf16x8 s; } u0, u1;
        u0.i = pack8(p0[0], p0[1]);
        u1.i = pack8(p1[0], p1[1]);
        a00 = mfma16(u0.s, u0.s, a00);
        a01 = mfma16(u0.s, u1.s, a01);
        a11 = mfma16(u1.s, u1.s, a11);
    }
    float lsum = 0.f;
    auto proc = [&](const f32x4& acc, int rb, int cb) {
        #pragma unroll
        for (int e = 0; e < 4; e++) {
            int i = rb * 16 + cg * 4 + e;
            int j = cb * 16 + lr;
            if (j > i) {
                float d2 = sq_out[(size_t)i * BDIM + b] + sq_out[(size_t)j * BDIM + b] - 2.f * acc[e];
                float d = sqrtf(fmaxf(d2, 0.f) + 1e-12f);
                lsum += fmaxf(1.f - d, 0.f);
            }
        }
    };
    proc(a00, 0, 0); proc(a01, 0, 1); proc(a11, 1, 1);
    lsum = wave_sum(lsum);
    if (l == 0) atomicAdd(accum, lsum);
}

__global__ void init_k(float* sums) { sums[threadIdx.x] = 0.f; }

__global__ void fin_k(const float* __restrict__ sums, float* __restrict__ out) {
    float sl = sums[0] * (1.0f / 33554432.0f);
    float sec = sums[1] * (1.0f / (1024.0f * 496.0f));
    out[0] = 0.5f * sl + 0.5f * sec;
    out[1] = sl;
    out[2] = sec;
}

extern "C" void kernel_launch(void* const* d_in, const int* in_sizes, int n_in,
                              void* d_out, int out_size, void* d_ws, size_t ws_size,
                              hipStream_t stream) {
    const float* outputs = (const float*)d_in[0];   // [32,1024,1024] f32
    const float* enc     = (const float*)d_in[1];   // [1024,1024] f32
    float* out = (float*)d_out;                     // 3 floats

    float* ps     = (float*)d_ws;
    float* psec   = ps + 1536;
    float* sq_out = ps + 2048;
    float* sq_enc = sq_out + N_SEC * BDIM;
    float* dsent  = sq_enc + BDIM;
    unsigned short* Xbf = (unsigned short*)(dsent + (size_t)BDIM * BDIM);
    unsigned short* Ebf = Xbf + (size_t)N_SEC * BDIM * DDIM;

    const size_t NEED = 4 * (2048 + (size_t)N_SEC * BDIM + BDIM + (size_t)BDIM * BDIM)
                      + 2 * ((size_t)N_SEC * BDIM * DDIM + (size_t)BDIM * DDIM);

    if (ws_size >= NEED) {
        hipLaunchKernelGGL(prep_k, dim3((N_SEC * BDIM + BDIM) / 4), dim3(256), 0, stream,
                           outputs, enc, Xbf, Ebf, sq_out, sq_enc);
        hipLaunchKernelGGL(zero_k, dim3(512), dim3(256), 0, stream, dsent);
        hipLaunchKernelGGL((gram8_k<2, 8>), dim3(36 * 4), dim3(256), 0, stream,
                           Ebf, sq_enc, (const float*)nullptr, dsent, (float*)nullptr, 0);
        hipLaunchKernelGGL(cvt0_k, dim3(512), dim3(256), 0, stream, dsent, sq_enc);
        hipLaunchKernelGGL(gramF_k, dim3(36 * N_SEC), dim3(256), 0, stream,
                           Xbf, sq_out, dsent, ps);
        hipLaunchKernelGGL(secret4_k, dim3(BDIM / 4), dim3(256), 0, stream,
                           Xbf, sq_out, psec);
        hipLaunchKernelGGL(fin2_k, dim3(1), dim3(256), 0, stream, ps, psec, out);
    } else {
        float* sums = (float*)d_ws;
        float* fsq_out = sums + 64;
        float* fsq_enc = fsq_out + N_SEC * BDIM;
        float* fdsent  = fsq_enc + BDIM;
        hipLaunchKernelGGL(init_k, dim3(1), dim3(2), 0, stream, sums);
        hipLaunchKernelGGL(norms_k, dim3((N_SEC * BDIM + BDIM) / 4), dim3(256), 0, stream,
                           outputs, enc, fsq_out, fsq_enc);
        hipLaunchKernelGGL((gram_k<0>), dim3(36), dim3(256), 0, stream,
                           enc, fsq_enc, (const float*)nullptr, fdsent, (float*)nullptr);
        hipLaunchKernelGGL((gram_k<1>), dim3(36, N_SEC), dim3(256), 0, stream,
                           outputs, fsq_out, (const float*)fdsent, (float*)nullptr, &sums[0]);
        hipLaunchKernelGGL(secret_k, dim3(BDIM / 4), dim3(256), 0, stream,
                           outputs, fsq_out, &sums[1]);
        hipLaunchKernelGGL(fin_k, dim3(1), dim3(1), 0, stream, sums, out);
    }
}

// Round 15
// 135.645 us; speedup vs baseline: 1.1912x; 1.0711x over previous
//
#include <hip/hip_runtime.h>
#include <hip/hip_bf16.h>

#define N_SEC 32
#define BDIM 1024
#define DDIM 1024

typedef __attribute__((ext_vector_type(8))) short bf16x8;
typedef __attribute__((ext_vector_type(4))) float f32x4;
typedef __attribute__((ext_vector_type(4))) int i32x4;

#define WAITVM(n) asm volatile("s_waitcnt vmcnt(" #n ")" ::: "memory")

__device__ __forceinline__ void bar() {           // raw barrier + compiler fence
    __builtin_amdgcn_s_barrier();                 // (NO sched_barrier - m141)
    asm volatile("" ::: "memory");
}

__device__ __forceinline__ unsigned pk2(float a, float b) {
    union { __hip_bfloat162 h; unsigned u; } cv;
    cv.h = __float22bfloat162_rn(make_float2(a, b));
    return cv.u;
}

__device__ __forceinline__ i32x4 pack8(float4 a, float4 b) {
    i32x4 r;
    r[0] = pk2(a.x, a.y); r[1] = pk2(a.z, a.w);
    r[2] = pk2(b.x, b.y); r[3] = pk2(b.z, b.w);
    return r;
}

__device__ __forceinline__ f32x4 mfma16(bf16x8 a, bf16x8 b, f32x4 c) {
    return __builtin_amdgcn_mfma_f32_16x16x32_bf16(a, b, c, 0, 0, 0);
}

__device__ __forceinline__ float wave_sum(float v) {
    #pragma unroll
    for (int off = 32; off > 0; off >>= 1) v += __shfl_down(v, off, 64);
    return v;
}

__device__ __forceinline__ void gload16(const unsigned short* g, unsigned short* l) {
    __builtin_amdgcn_global_load_lds(
        (const __attribute__((address_space(1))) unsigned int*)g,
        (__attribute__((address_space(3))) unsigned int*)l, 16, 0, 0);
}

// ---------------------------------------------------------------------------
// Path A: prep, zero, gram8<2> (enc split-K, atomic gram), cvt0,
// gramF2 (2-buffer double-light-barrier, EXACTLY 32KB LDS -> 5 blk/CU ->
// all 1152 blocks resident in ONE scheduling round), secret4, fin2.
// ---------------------------------------------------------------------------

__global__ void prep_k(const float* __restrict__ outp, const float* __restrict__ enc,
                       unsigned short* __restrict__ Xb, unsigned short* __restrict__ Eb,
                       float* __restrict__ sq_out, float* __restrict__ sq_enc) {
    int wid = threadIdx.x >> 6, l = threadIdx.x & 63;
    int r = blockIdx.x * 4 + wid;
    bool isOut = r < N_SEC * BDIM;
    const float* src = isOut ? (outp + (size_t)r * DDIM)
                             : (enc + (size_t)(r - N_SEC * BDIM) * DDIM);
    unsigned short* dst = isOut ? (Xb + (size_t)r * DDIM)
                                : (Eb + (size_t)(r - N_SEC * BDIM) * DDIM);
    const float4* s4 = (const float4*)src;
    float s = 0.f;
    #pragma unroll
    for (int h = 0; h < 2; ++h) {
        int c = l + h * 64;
        float4 v0 = s4[2 * c], v1 = s4[2 * c + 1];
        i32x4 p = pack8(v0, v1);
        *(i32x4*)&dst[c * 8] = p;
        #pragma unroll
        for (int e = 0; e < 4; ++e) {
            unsigned u = (unsigned)p[e];
            float a = __uint_as_float(u << 16);
            float b = __uint_as_float(u & 0xFFFF0000u);
            s += a * a + b * b;
        }
    }
    s = wave_sum(s);
    if (l == 0) { if (isOut) sq_out[r] = s; else sq_enc[r - N_SEC * BDIM] = s; }
}

__global__ void zero_k(float* __restrict__ p) {
    int i = blockIdx.x * blockDim.x + threadIdx.x;       // 512*256*2 = 256K f4
    float4 z = {0.f, 0.f, 0.f, 0.f};
    ((float4*)p)[i] = z;
    ((float4*)p)[i + 131072] = z;
}

// In-place: g -> sqrt(max(sq[i]+sq[j]-2g,0)+eps) over the 1024x1024 plane.
__global__ void cvt0_k(float* __restrict__ d, const float* __restrict__ sq) {
    int t = blockIdx.x * blockDim.x + threadIdx.x;       // 512 blocks * 256
    #pragma unroll
    for (int h = 0; h < 2; ++h) {
        int idx = t + h * 131072;                        // float4 index
        int i = idx >> 8;
        float si = sq[i];
        float4 g = ((const float4*)d)[idx];
        int j0 = (idx & 255) * 4;
        float4 r;
        r.x = sqrtf(fmaxf(si + sq[j0 + 0] - 2.f * g.x, 0.f) + 1e-12f);
        r.y = sqrtf(fmaxf(si + sq[j0 + 1] - 2.f * g.y, 0.f) + 1e-12f);
        r.z = sqrtf(fmaxf(si + sq[j0 + 2] - 2.f * g.z, 0.f) + 1e-12f);
        r.w = sqrtf(fmaxf(si + sq[j0 + 3] - 2.f * g.w, 0.f) + 1e-12f);
        ((float4*)d)[idx] = r;
    }
}

// enc gram, split-K: 36 upper tiles x 4 K-slices, 3-buffer counted-vmcnt.
// MODE 2: K-slice [kbeg,kbeg+NIT), atomicAdd raw gram into dsent_w.
template<int MODE, int NIT>
__global__ void gram8_k(const unsigned short* __restrict__ Xb, const float* __restrict__ sqv,
                        const float* __restrict__ dsent_r, float* __restrict__ dsent_w,
                        float* __restrict__ partials, int kbeg_base) {
    int n, tile, kbeg;
    if (MODE == 1) {
        int g = blockIdx.x;
        int xcd = g & 7, local = g >> 3;
        n = xcd * 4 + local / 36;
        tile = local % 36;
        kbeg = 0;
    } else {
        n = 0;
        tile = blockIdx.x >> 2;
        kbeg = (blockIdx.x & 3) * NIT;
        (void)kbeg_base;
    }
    int idx = tile, ti = 0;
    while (idx >= 8 - ti) { idx -= 8 - ti; ti++; }
    int tj = ti + idx;
    const unsigned short* Xn = Xb + (size_t)n * BDIM * DDIM;
    const float* sqn = sqv + n * BDIM;
    int i0 = ti * 128, j0 = tj * 128;
    bool diag = (ti == tj);

    __shared__ __align__(16) unsigned short Ash[3][4096];   // 3 x 8KB
    __shared__ __align__(16) unsigned short Bsh[3][4096];
    __shared__ float red[4];

    int t = threadIdx.x, wid = t >> 6, l = t & 63;
    int wr = wid >> 1, wc = wid & 1;
    bool dead = diag && (wr > wc);
    int cg = l >> 4, lr = l & 15;

    f32x4 acc[4][4];
    #pragma unroll
    for (int a = 0; a < 4; a++)
        #pragma unroll
        for (int c = 0; c < 4; c++) acc[a][c] = f32x4{0.f, 0.f, 0.f, 0.f};

    int eoffA[4], eoffB[4];
    #pragma unroll
    for (int f = 0; f < 4; f++) {
        int ra = wr * 64 + f * 16 + lr;
        eoffA[f] = ra * 32 + ((cg ^ ((ra >> 1) & 3)) * 8);
        int rb = wc * 64 + f * 16 + lr;
        eoffB[f] = rb * 32 + ((cg ^ ((rb >> 1) & 3)) * 8);
    }

    int rs = wid * 16 + (l >> 2);
    int cgs = (l & 3) ^ ((rs >> 1) & 3);
    const unsigned short* gA0 = Xn + (size_t)(i0 + rs) * DDIM + cgs * 8;
    const unsigned short* gA1 = gA0 + (size_t)64 * DDIM;
    const unsigned short* gB0 = Xn + (size_t)(j0 + rs) * DDIM + cgs * 8;
    const unsigned short* gB1 = gB0 + (size_t)64 * DDIM;

    auto stage = [&](int buf, int kt) {
        int ko = kt * 32;
        gload16(gA0 + ko, &Ash[buf][wid * 512]);
        gload16(gA1 + ko, &Ash[buf][2048 + wid * 512]);
        gload16(gB0 + ko, &Bsh[buf][wid * 512]);
        gload16(gB1 + ko, &Bsh[buf][2048 + wid * 512]);
    };
    auto compute = [&](int buf) {
        if (dead) return;
        bf16x8 af[4], bfr[4];
        #pragma unroll
        for (int f = 0; f < 4; f++) {
            af[f]  = *(const bf16x8*)&Ash[buf][eoffA[f]];
            bfr[f] = *(const bf16x8*)&Bsh[buf][eoffB[f]];
        }
        #pragma unroll
        for (int fi = 0; fi < 4; fi++)
            #pragma unroll
            for (int fj = 0; fj < 4; fj++) {
                if (diag && wr == wc && fj < fi) continue;
                acc[fi][fj] = mfma16(af[fi], bfr[fj], acc[fi][fj]);
            }
    };

    int klast = kbeg + NIT - 1;
#define GSTEP(SB, CB) do {                       \
        int nx = c + 1; if (nx > klast) nx = klast; \
        stage(SB, nx);                           \
        WAITVM(4);                               \
        bar();                                   \
        compute(CB);                             \
        ++c; } while (0)

    stage(0, kbeg);
    int c = kbeg;
    #pragma unroll 1
    for (int it = 0; it < NIT / 3; ++it) {
        GSTEP(1, 0);
        GSTEP(2, 1);
        GSTEP(0, 2);
    }
    if (NIT % 3 >= 1) GSTEP(1, 0);
    if (NIT % 3 >= 2) GSTEP(2, 1);
#undef GSTEP
    asm volatile("s_waitcnt vmcnt(0)" ::: "memory");

    float lsum = 0.f;
    if (!dead) {
        #pragma unroll
        for (int fi = 0; fi < 4; fi++) {
            #pragma unroll
            for (int fj = 0; fj < 4; fj++) {
                if (diag && wr == wc && fj < fi) continue;
                int jg = j0 + wc * 64 + fj * 16 + lr;
                #pragma unroll
                for (int e = 0; e < 4; e++) {
                    int ig = i0 + wr * 64 + fi * 16 + cg * 4 + e;
                    float g = acc[fi][fj][e];
                    if (MODE == 2) {
                        atomicAdd(&dsent_w[(size_t)ig * BDIM + jg], g);
                    } else {
                        float d2 = sqn[ig] + sqn[jg] - 2.f * g;
                        float d = sqrtf(fmaxf(d2, 0.f) + 1e-12f);
                        if (!diag || jg > ig) {
                            float diff = d - dsent_r[(size_t)ig * BDIM + jg];
                            lsum += diff * diff;
                        }
                    }
                }
            }
        }
    }
    if (MODE == 1) {
        lsum = wave_sum(lsum * 2.f);
        if (l == 0) red[wid] = lsum;
        __syncthreads();
        if (t == 0) partials[blockIdx.x] = red[0] + red[1] + red[2] + red[3];
    }
}

// Main gram: 128^2 triangle tile, 4 waves, BK=32, 2-buffer double-light-barrier:
//   {bar1; stage(kt+1 -> buf^1); vmcnt(4); bar2; compute(kt)}
// LDS is EXACTLY 32768 B (no separate red[] - reduction reuses SH after the
// final drain; red slot = buffer-0 bytes 0..15, last READ before the final
// barrier pair while the last compute touches only buffer 1 -> no overlap).
// 160KB/32KB = 5 blocks/CU -> 1280 resident >= 1152 -> single round.
__global__ void gramF2_k(const unsigned short* __restrict__ Xb,
                         const float* __restrict__ sq_out,
                         const float* __restrict__ dsent,
                         float* __restrict__ ps) {
    __shared__ __align__(16) unsigned short SH[16384];   // exactly 32 KB
    int t = threadIdx.x, wid = t >> 6, l = t & 63;
    int cg = l >> 4, lr = l & 15;

    int g = blockIdx.x;                       // 0..1151
    int xcd = g & 7, local = g >> 3;
    int n = xcd * 4 + local / 36;             // 4 consecutive n per XCD
    int tile = local % 36;
    int idx = tile, ti = 0;
    while (idx >= 8 - ti) { idx -= 8 - ti; ti++; }
    int tj = ti + idx;
    const unsigned short* Xn = Xb + (size_t)n * BDIM * DDIM;
    const float* sqn = sq_out + n * BDIM;
    int i0 = ti * 128, j0 = tj * 128;
    bool diag = (ti == tj);

    int wr = wid >> 1, wc = wid & 1;
    bool dead = diag && (wr > wc);

    f32x4 acc[4][4];
    #pragma unroll
    for (int a = 0; a < 4; a++)
        #pragma unroll
        for (int c = 0; c < 4; c++) acc[a][c] = f32x4{0.f, 0.f, 0.f, 0.f};

    int eoffA[4], eoffB[4];
    #pragma unroll
    for (int f = 0; f < 4; f++) {
        int ra = wr * 64 + f * 16 + lr;
        eoffA[f] = ra * 32 + ((cg ^ ((ra >> 1) & 3)) * 8);
        int rb = wc * 64 + f * 16 + lr;
        eoffB[f] = rb * 32 + ((cg ^ ((rb >> 1) & 3)) * 8);
    }

    int rs = wid * 16 + (l >> 2);
    int cgs = (l & 3) ^ ((rs >> 1) & 3);
    const unsigned short* gA0 = Xn + (size_t)(i0 + rs) * DDIM + cgs * 8;
    const unsigned short* gA1 = gA0 + (size_t)64 * DDIM;
    const unsigned short* gB0 = Xn + (size_t)(j0 + rs) * DDIM + cgs * 8;
    const unsigned short* gB1 = gB0 + (size_t)64 * DDIM;

    auto stage = [&](int buf, int kt) {       // 4 VMEM ops per thread
        int ko = kt * 32;
        gload16(gA0 + ko, &SH[buf * 4096 + wid * 512]);
        gload16(gA1 + ko, &SH[buf * 4096 + 2048 + wid * 512]);
        gload16(gB0 + ko, &SH[8192 + buf * 4096 + wid * 512]);
        gload16(gB1 + ko, &SH[8192 + buf * 4096 + 2048 + wid * 512]);
    };
    auto compute = [&](int buf) {
        if (dead) return;
        bf16x8 af[4], bfr[4];
        #pragma unroll
        for (int f = 0; f < 4; f++) {
            af[f]  = *(const bf16x8*)&SH[buf * 4096 + eoffA[f]];
            bfr[f] = *(const bf16x8*)&SH[8192 + buf * 4096 + eoffB[f]];
        }
        #pragma unroll
        for (int fi = 0; fi < 4; fi++)
            #pragma unroll
            for (int fj = 0; fj < 4; fj++) {
                if (diag && wr == wc && fj < fi) continue;
                acc[fi][fj] = mfma16(af[fi], bfr[fj], acc[fi][fj]);
            }
    };

#define GSTEP(NB, CB) do {                       \
        bar();                                   \
        int nx = c + 1; if (nx > 31) nx = 31;    \
        stage(NB, nx);                           \
        WAITVM(4);                               \
        bar();                                   \
        compute(CB);                             \
        ++c; } while (0)

    stage(0, 0);
    int c = 0;
    #pragma unroll 1
    for (int it = 0; it < 16; ++it) {            // 32 computes, tiles 0..31
        GSTEP(1, 0);
        GSTEP(0, 1);
    }
#undef GSTEP
    asm volatile("s_waitcnt vmcnt(0)" ::: "memory");   // drain before exit

    float lsum = 0.f;
    if (!dead) {
        #pragma unroll
        for (int fi = 0; fi < 4; fi++) {
            #pragma unroll
            for (int fj = 0; fj < 4; fj++) {
                if (diag && wr == wc && fj < fi) continue;
                int jg = j0 + wc * 64 + fj * 16 + lr;
                #pragma unroll
                for (int e = 0; e < 4; e++) {
                    int ig = i0 + wr * 64 + fi * 16 + cg * 4 + e;
                    float gg = acc[fi][fj][e];
                    float d2 = sqn[ig] + sqn[jg] - 2.f * gg;
                    float d = sqrtf(fmaxf(d2, 0.f) + 1e-12f);
                    if (!diag || jg > ig) {
                        float diff = d - dsent[(size_t)ig * BDIM + jg];
                        lsum += diff * diff;
                    }
                }
            }
        }
    }
    lsum = wave_sum(lsum * 2.f);                 // strict upper counted twice
    float* redf = (float*)SH;                    // reuse LDS (buffers dead now)
    if (l == 0) redf[wid] = lsum;
    __syncthreads();
    if (t == 0) ps[g] = redf[0] + redf[1] + redf[2] + redf[3];
}

// Batched per-b 32x32 gram, 2-phase dbuf. Per-block partial output.
__global__ void secret4_k(const unsigned short* __restrict__ Xb,
                          const float* __restrict__ sq_out, float* __restrict__ partials) {
    __shared__ __align__(16) unsigned short S[2][32 * 4 * 128];
    __shared__ float red[4];
    int t = threadIdx.x, wid = t >> 6, l = t & 63;
    int b0 = blockIdx.x * 4;
    int cg = l >> 4, lr = l & 15;
    f32x4 a00 = {0.f,0.f,0.f,0.f}, a01 = {0.f,0.f,0.f,0.f}, a11 = {0.f,0.f,0.f,0.f};

    auto stage = [&](int buf, int kt) {
        #pragma unroll
        for (int m = 0; m < 8; ++m) {
            int n = m * 4 + wid;
            gload16(Xb + ((size_t)(n * BDIM + b0 + cg)) * DDIM + kt * 128 + ((lr ^ (n & 7)) * 8),
                    &S[buf][n * 512]);
        }
    };
    auto compute = [&](int buf) {
        #pragma unroll
        for (int k2 = 0; k2 < 4; ++k2) {
            int cs = k2 * 4 + cg;
            int cl = (cs ^ (lr & 7)) * 8;
            bf16x8 u0 = *(const bf16x8*)&S[buf][lr * 512 + wid * 128 + cl];
            bf16x8 u1 = *(const bf16x8*)&S[buf][(16 + lr) * 512 + wid * 128 + cl];
            a00 = mfma16(u0, u0, a00);
            a01 = mfma16(u0, u1, a01);
            a11 = mfma16(u1, u1, a11);
        }
    };

    stage(0, 0);
    __syncthreads();
    for (int kt = 0; kt < 6; kt += 2) {
        stage(1, kt + 1);
        compute(0);
        __syncthreads();
        stage(0, kt + 2);
        compute(1);
        __syncthreads();
    }
    stage(1, 7);
    compute(0);
    __syncthreads();
    compute(1);

    float lsum = 0.f;
    int b = b0 + wid;
    auto proc = [&](const f32x4& acc, int rb, int cb) {
        #pragma unroll
        for (int e = 0; e < 4; e++) {
            int i = rb * 16 + cg * 4 + e;
            int j = cb * 16 + lr;
            if (j > i) {
                float d2 = sq_out[(size_t)i * BDIM + b] + sq_out[(size_t)j * BDIM + b] - 2.f * acc[e];
                float d = sqrtf(fmaxf(d2, 0.f) + 1e-12f);
                lsum += fmaxf(1.f - d, 0.f);
            }
        }
    };
    proc(a00, 0, 0); proc(a01, 0, 1); proc(a11, 1, 1);
    lsum = wave_sum(lsum);
    if (l == 0) red[wid] = lsum;
    __syncthreads();
    if (t == 0) partials[blockIdx.x] = red[0] + red[1] + red[2] + red[3];
}

// Reduce partials (1152 sentence + 256 secret) and write the 3 outputs.
__global__ void fin2_k(const float* __restrict__ ps, const float* __restrict__ psec,
                       float* __restrict__ out) {
    __shared__ float red[16];
    int t = threadIdx.x;
    float s = 0.f;
    for (int i = t; i < 36 * N_SEC; i += 256) s += ps[i];
    float s2 = psec[t];
    s = wave_sum(s);
    s2 = wave_sum(s2);
    if ((t & 63) == 0) { red[t >> 6] = s; red[8 + (t >> 6)] = s2; }
    __syncthreads();
    if (t == 0) {
        float a = red[0] + red[1] + red[2] + red[3];
        float b = red[8] + red[9] + red[10] + red[11];
        float sl = a * (1.0f / 33554432.0f);           // / (N*B*B)
        float sec = b * (1.0f / (1024.0f * 496.0f));   // / B / n_pairs
        out[0] = 0.5f * sl + 0.5f * sec;
        out[1] = sl;
        out[2] = sec;
    }
}

// ---------------------------------------------------------------------------
// Path B (fallback, known-good): fp32 reads + in-loop convert.
// ---------------------------------------------------------------------------

__global__ void norms_k(const float* __restrict__ outp, const float* __restrict__ enc,
                        float* __restrict__ sq_out, float* __restrict__ sq_enc) {
    int wid = threadIdx.x >> 6, l = threadIdx.x & 63;
    int r = blockIdx.x * 4 + wid;
    const float* src = (r < N_SEC * BDIM) ? (outp + (size_t)r * DDIM)
                                          : (enc + (size_t)(r - N_SEC * BDIM) * DDIM);
    float s = 0.f;
    #pragma unroll
    for (int q = 0; q < 4; q++) {
        float4 v = reinterpret_cast<const float4*>(src)[l + q * 64];
        unsigned u0 = pk2(v.x, v.y), u1 = pk2(v.z, v.w);
        float a = __uint_as_float(u0 << 16), b = __uint_as_float(u0 & 0xFFFF0000u);
        float c = __uint_as_float(u1 << 16), d = __uint_as_float(u1 & 0xFFFF0000u);
        s += a * a + b * b + c * c + d * d;
    }
    s = wave_sum(s);
    if (l == 0) { if (r < N_SEC * BDIM) sq_out[r] = s; else sq_enc[r - N_SEC * BDIM] = s; }
}

template<int MODE>
__global__ void gram_k(const float* __restrict__ X, const float* __restrict__ sqv,
                       const float* __restrict__ dsent_r, float* __restrict__ dsent_w,
                       float* __restrict__ accum) {
    int idx = blockIdx.x, ti = 0;
    while (idx >= 8 - ti) { idx -= 8 - ti; ti++; }
    int tj = ti + idx;
    int n = (MODE == 1) ? blockIdx.y : 0;
    const float* Xn = X + (size_t)n * BDIM * DDIM;
    const float* sqn = sqv + n * BDIM;
    int i0 = ti * 128, j0 = tj * 128;
    bool diag = (ti == tj);
    __shared__ __align__(16) unsigned short Ash[128 * 32];
    __shared__ __align__(16) unsigned short Bsh[128 * 32];
    int t = threadIdx.x, wid = t >> 6, l = t & 63;
    int wr = wid >> 1, wc = wid & 1;
    bool dead = diag && (wr > wc);
    int cg = l >> 4, lr = l & 15;
    f32x4 acc[4][4];
    #pragma unroll
    for (int a = 0; a < 4; a++)
        #pragma unroll
        for (int c = 0; c < 4; c++) acc[a][c] = f32x4{0.f, 0.f, 0.f, 0.f};
    int r0 = t >> 2, c0 = t & 3;
    int swz0 = (c0 ^ (r0 & 3)) * 8;
    int off0 = r0 * 32 + swz0;
    int off1 = (r0 + 64) * 32 + swz0;
    for (int kt = 0; kt < DDIM / 32; ++kt) {
        int k0 = kt * 32;
        const float4* pa0 = (const float4*)(Xn + (size_t)(i0 + r0) * DDIM + k0 + c0 * 8);
        const float4* pa1 = (const float4*)(Xn + (size_t)(i0 + r0 + 64) * DDIM + k0 + c0 * 8);
        const float4* pb0 = (const float4*)(Xn + (size_t)(j0 + r0) * DDIM + k0 + c0 * 8);
        const float4* pb1 = (const float4*)(Xn + (size_t)(j0 + r0 + 64) * DDIM + k0 + c0 * 8);
        float4 a00 = pa0[0], a01 = pa0[1];
        float4 a10 = pa1[0], a11 = pa1[1];
        float4 b00 = pb0[0], b01 = pb0[1];
        float4 b10 = pb1[0], b11 = pb1[1];
        __syncthreads();
        *(i32x4*)&Ash[off0] = pack8(a00, a01);
        *(i32x4*)&Ash[off1] = pack8(a10, a11);
        *(i32x4*)&Bsh[off0] = pack8(b00, b01);
        *(i32x4*)&Bsh[off1] = pack8(b10, b11);
        __syncthreads();
        if (!dead) {
            bf16x8 af[4], bfr[4];
            #pragma unroll
            for (int f = 0; f < 4; f++) {
                int ra = wr * 64 + f * 16 + lr;
                af[f] = *(const bf16x8*)&Ash[ra * 32 + ((cg ^ (ra & 3)) * 8)];
                int rb = wc * 64 + f * 16 + lr;
                bfr[f] = *(const bf16x8*)&Bsh[rb * 32 + ((cg ^ (rb & 3)) * 8)];
            }
            #pragma unroll
            for (int fi = 0; fi < 4; fi++)
                #pragma unroll
                for (int fj = 0; fj < 4; fj++) {
                    if (diag && wr == wc && fj < fi) continue;
                    acc[fi][fj] = mfma16(af[fi], bfr[fj], acc[fi][fj]);
                }
        }
    }
    if (!dead) {
        float lsum = 0.f;
        #pragma unroll
        for (int fi = 0; fi < 4; fi++) {
            #pragma unroll
            for (int fj = 0; fj < 4; fj++) {
                if (diag && wr == wc && fj < fi) continue;
                int jg = j0 + wc * 64 + fj * 16 + lr;
                #pragma unroll
                for (int e = 0; e < 4; e++) {
                    int ig = i0 + wr * 64 + fi * 16 + cg * 4 + e;
                    float g = acc[fi][fj][e];
                    float d2 = sqn[ig] + sqn[jg] - 2.f * g;
                    float d = sqrtf(fmaxf(d2, 0.f) + 1e-12f);
                    if (MODE == 0) {
                        dsent_w[(size_t)ig * BDIM + jg] = d;
                    } else {
                        if (!diag || jg > ig) {
                            float diff = d - dsent_r[(size_t)ig * BDIM + jg];
                            lsum += diff * diff;
                        }
                    }
                }
            }
        }
        if (MODE == 1) {
            lsum = wave_sum(lsum * 2.f);
            if (l == 0) atomicAdd(accum, lsum);
        }
    }
}

__global__ void secret_k(const float* __restrict__ X, const float* __restrict__ sq_out,
                         float* __restrict__ accum) {
    int wid = threadIdx.x >> 6, l = threadIdx.x & 63;
    int b = blockIdx.x * 4 + wid;
    int cg = l >> 4, lr = l & 15;
    f32x4 a00 = {0.f,0.f,0.f,0.f}, a01 = {0.f,0.f,0.f,0.f}, a11 = {0.f,0.f,0.f,0.f};
    for (int kt = 0; kt < 32; ++kt) {
        int k0 = kt * 32 + cg * 8;
        const float4* p0 = (const float4*)(X + ((size_t)lr * BDIM + b) * DDIM + k0);
        const float4* p1 = (const float4*)(X + ((size_t)(16 + lr) * BDIM + b) * DDIM + k0);
        union { i32x4 i; bf16x8 s; } u0, u1;
        u0.i = pack8(p0[0], p0[1]);
        u1.i = pack8(p1[0], p1[1]);
        a00 = mfma16(u0.s, u0.s, a00);
        a01 = mfma16(u0.s, u1.s, a01);
        a11 = mfma16(u1.s, u1.s, a11);
    }
    float lsum = 0.f;
    auto proc = [&](const f32x4& acc, int rb, int cb) {
        #pragma unroll
        for (int e = 0; e < 4; e++) {
            int i = rb * 16 + cg * 4 + e;
            int j = cb * 16 + lr;
            if (j > i) {
                float d2 = sq_out[(size_t)i * BDIM + b] + sq_out[(size_t)j * BDIM + b] - 2.f * acc[e];
                float d = sqrtf(fmaxf(d2, 0.f) + 1e-12f);
                lsum += fmaxf(1.f - d, 0.f);
            }
        }
    };
    proc(a00, 0, 0); proc(a01, 0, 1); proc(a11, 1, 1);
    lsum = wave_sum(lsum);
    if (l == 0) atomicAdd(accum, lsum);
}

__global__ void init_k(float* sums) { sums[threadIdx.x] = 0.f; }

__global__ void fin_k(const float* __restrict__ sums, float* __restrict__ out) {
    float sl = sums[0] * (1.0f / 33554432.0f);
    float sec = sums[1] * (1.0f / (1024.0f * 496.0f));
    out[0] = 0.5f * sl + 0.5f * sec;
    out[1] = sl;
    out[2] = sec;
}

extern "C" void kernel_launch(void* const* d_in, const int* in_sizes, int n_in,
                              void* d_out, int out_size, void* d_ws, size_t ws_size,
                              hipStream_t stream) {
    const float* outputs = (const float*)d_in[0];   // [32,1024,1024] f32
    const float* enc     = (const float*)d_in[1];   // [1024,1024] f32
    float* out = (float*)d_out;                     // 3 floats

    float* ps     = (float*)d_ws;
    float* psec   = ps + 1536;
    float* sq_out = ps + 2048;
    float* sq_enc = sq_out + N_SEC * BDIM;
    float* dsent  = sq_enc + BDIM;
    unsigned short* Xbf = (unsigned short*)(dsent + (size_t)BDIM * BDIM);
    unsigned short* Ebf = Xbf + (size_t)N_SEC * BDIM * DDIM;

    const size_t NEED = 4 * (2048 + (size_t)N_SEC * BDIM + BDIM + (size_t)BDIM * BDIM)
                      + 2 * ((size_t)N_SEC * BDIM * DDIM + (size_t)BDIM * DDIM);

    if (ws_size >= NEED) {
        hipLaunchKernelGGL(prep_k, dim3((N_SEC * BDIM + BDIM) / 4), dim3(256), 0, stream,
                           outputs, enc, Xbf, Ebf, sq_out, sq_enc);
        hipLaunchKernelGGL(zero_k, dim3(512), dim3(256), 0, stream, dsent);
        hipLaunchKernelGGL((gram8_k<2, 8>), dim3(36 * 4), dim3(256), 0, stream,
                           Ebf, sq_enc, (const float*)nullptr, dsent, (float*)nullptr, 0);
        hipLaunchKernelGGL(cvt0_k, dim3(512), dim3(256), 0, stream, dsent, sq_enc);
        hipLaunchKernelGGL(gramF2_k, dim3(36 * N_SEC), dim3(256), 0, stream,
                           Xbf, sq_out, dsent, ps);
        hipLaunchKernelGGL(secret4_k, dim3(BDIM / 4), dim3(256), 0, stream,
                           Xbf, sq_out, psec);
        hipLaunchKernelGGL(fin2_k, dim3(1), dim3(256), 0, stream, ps, psec, out);
    } else {
        float* sums = (float*)d_ws;
        float* fsq_out = sums + 64;
        float* fsq_enc = fsq_out + N_SEC * BDIM;
        float* fdsent  = fsq_enc + BDIM;
        hipLaunchKernelGGL(init_k, dim3(1), dim3(2), 0, stream, sums);
        hipLaunchKernelGGL(norms_k, dim3((N_SEC * BDIM + BDIM) / 4), dim3(256), 0, stream,
                           outputs, enc, fsq_out, fsq_enc);
        hipLaunchKernelGGL((gram_k<0>), dim3(36), dim3(256), 0, stream,
                           enc, fsq_enc, (const float*)nullptr, fdsent, (float*)nullptr);
        hipLaunchKernelGGL((gram_k<1>), dim3(36, N_SEC), dim3(256), 0, stream,
                           outputs, fsq_out, (const float*)fdsent, (float*)nullptr, &sums[0]);
        hipLaunchKernelGGL(secret_k, dim3(BDIM / 4), dim3(256), 0, stream,
                           outputs, fsq_out, &sums[1]);
        hipLaunchKernelGGL(fin_k, dim3(1), dim3(1), 0, stream, sums, out);
    }
}